// Round 2
// baseline (2156.770 us; speedup 1.0000x reference)
//
#include <hip/hip_runtime.h>
#include <float.h>
#include <math.h>

// PoseHeadBlock: FiLM -> SA(J=16) -> masked token CA (L=2048, via transpose trick)
//             -> spatial CA (S=256, same trick) -> FFN(GELU exact)
// All f32 VALU this round (correctness baseline). Transpose trick avoids the
// 137 GFLOP K/V projections; LN of kv fused into GEMM B-loads via row stats.

#define Bn 16
#define Jn 16
#define Ln 2048
#define Sn 256
#define Dn 1024
#define Hn 16
#define HDn 64
#define NSn 4

static const float EPSf = 1e-5f;
static const float SCALEf = 0.125f; // 1/sqrt(64)

typedef float4 f4;

__device__ __forceinline__ float wave_sum(float v) {
#pragma unroll
  for (int o = 32; o; o >>= 1) v += __shfl_xor(v, o);
  return v;
}
__device__ __forceinline__ float wave_max(float v) {
#pragma unroll
  for (int o = 32; o; o >>= 1) v = fmaxf(v, __shfl_xor(v, o));
  return v;
}

// sum-reduce two values across a 256-thread block; result broadcast to all.
__device__ __forceinline__ void block_reduce2(float& a, float& b) {
  __shared__ float la[4], lb[4];
  a = wave_sum(a); b = wave_sum(b);
  int t = threadIdx.x, w = t >> 6;
  __syncthreads();
  if ((t & 63) == 0) { la[w] = a; lb[w] = b; }
  __syncthreads();
  a = la[0] + la[1] + la[2] + la[3];
  b = lb[0] + lb[1] + lb[2] + lb[3];
}
__device__ __forceinline__ float block_max_bcast(float v) {
  __shared__ float lm[4];
  v = wave_max(v);
  int t = threadIdx.x;
  __syncthreads();
  if ((t & 63) == 0) lm[t >> 6] = v;
  __syncthreads();
  return fmaxf(fmaxf(lm[0], lm[1]), fmaxf(lm[2], lm[3]));
}
__device__ __forceinline__ float block_sum_bcast(float v) {
  __shared__ float ls[4];
  v = wave_sum(v);
  int t = threadIdx.x;
  __syncthreads();
  if ((t & 63) == 0) ls[t >> 6] = v;
  __syncthreads();
  return ls[0] + ls[1] + ls[2] + ls[3];
}

// ---- mask dtype probe: harness may pass bool as int32 or as raw uint8 ----
// Reads first 4096 int32 (16KB; safe either way). If any value outside {0,1},
// the buffer must be packed uint8 bools. flag = 1 -> int32, 0 -> uint8.
__global__ __launch_bounds__(256) void k_probe(const int* __restrict__ tm, int* flag) {
  __shared__ int bad;
  int t = threadIdx.x;
  if (t == 0) bad = 0;
  __syncthreads();
  int loc = 0;
  for (int i = t; i < 4096; i += 256) {
    unsigned v = (unsigned)tm[i];
    if (v > 1u) loc = 1;
  }
  if (loc) bad = 1;
  __syncthreads();
  if (t == 0) *flag = bad ? 0 : 1;
}

// ---- per-row mean/rstd over D=1024 (for fusing LN into GEMM loads) ----
__global__ __launch_bounds__(256) void k_rowstats(const float* __restrict__ x,
                                                  float* __restrict__ mean,
                                                  float* __restrict__ rstd) {
  int row = blockIdx.x, t = threadIdx.x;
  f4 v = *(const f4*)(x + (size_t)row * Dn + t * 4);
  float s = v.x + v.y + v.z + v.w;
  float s2 = v.x * v.x + v.y * v.y + v.z * v.z + v.w * v.w;
  block_reduce2(s, s2);
  if (t == 0) {
    float m = s * (1.f / Dn);
    float var = s2 * (1.f / Dn) - m * m;
    if (var < 0.f) var = 0.f;
    mean[row] = m;
    rstd[row] = rsqrtf(var + EPSf);
  }
}

// ---- film = cond @ film_w + film_b ; [B,2048] ----
__global__ __launch_bounds__(256) void k_film(const float* __restrict__ cond,
                                              const float* __restrict__ fw,
                                              const float* __restrict__ fb,
                                              float* __restrict__ film) {
  int b = blockIdx.y;
  int t = threadIdx.x;
  int n = blockIdx.x * 256 + t;
  __shared__ float cs[512];
  cs[t] = cond[b * 512 + t];
  cs[t + 256] = cond[b * 512 + 256 + t];
  __syncthreads();
  float acc = fb[n];
  for (int k = 0; k < 512; k++) acc = fmaf(cs[k], fw[(size_t)k * 2048 + n], acc);
  film[b * 2048 + n] = acc;
}

// ---- h' = h*(1+s)+sh -> hs ; xn = LN(h', g, b) ----
__global__ __launch_bounds__(256) void k_film_apply_ln(
    const float* __restrict__ h, const float* __restrict__ film,
    const float* __restrict__ g, const float* __restrict__ be,
    float* __restrict__ hs, float* __restrict__ xn) {
  int row = blockIdx.x, t = threadIdx.x, b = row >> 4;
  int c = t * 4;
  f4 hv = *(const f4*)(h + (size_t)row * Dn + c);
  f4 sv = *(const f4*)(film + (size_t)b * 2048 + c);
  f4 shv = *(const f4*)(film + (size_t)b * 2048 + 1024 + c);
  f4 v;
  v.x = hv.x * (1.f + sv.x) + shv.x;
  v.y = hv.y * (1.f + sv.y) + shv.y;
  v.z = hv.z * (1.f + sv.z) + shv.z;
  v.w = hv.w * (1.f + sv.w) + shv.w;
  *(f4*)(hs + (size_t)row * Dn + c) = v;
  float s = v.x + v.y + v.z + v.w;
  float s2 = v.x * v.x + v.y * v.y + v.z * v.z + v.w * v.w;
  block_reduce2(s, s2);
  float m = s * (1.f / Dn);
  float var = s2 * (1.f / Dn) - m * m;
  var = fmaxf(var, 0.f);
  float rs = rsqrtf(var + EPSf);
  f4 o;
  o.x = (v.x - m) * rs * g[c + 0] + be[c + 0];
  o.y = (v.y - m) * rs * g[c + 1] + be[c + 1];
  o.z = (v.z - m) * rs * g[c + 2] + be[c + 2];
  o.w = (v.w - m) * rs * g[c + 3] + be[c + 3];
  *(f4*)(xn + (size_t)row * Dn + c) = o;
}

// ---- generic row LN (D=1024) ----
__global__ __launch_bounds__(256) void k_ln(const float* __restrict__ x,
                                            float* __restrict__ y,
                                            const float* __restrict__ g,
                                            const float* __restrict__ be) {
  int row = blockIdx.x, t = threadIdx.x;
  int c = t * 4;
  f4 v = *(const f4*)(x + (size_t)row * Dn + c);
  float s = v.x + v.y + v.z + v.w;
  float s2 = v.x * v.x + v.y * v.y + v.z * v.z + v.w * v.w;
  block_reduce2(s, s2);
  float m = s * (1.f / Dn);
  float var = s2 * (1.f / Dn) - m * m;
  var = fmaxf(var, 0.f);
  float rs = rsqrtf(var + EPSf);
  f4 o;
  o.x = (v.x - m) * rs * g[c + 0] + be[c + 0];
  o.y = (v.y - m) * rs * g[c + 1] + be[c + 1];
  o.z = (v.z - m) * rs * g[c + 2] + be[c + 2];
  o.w = (v.w - m) * rs * g[c + 3] + be[c + 3];
  *(f4*)(y + (size_t)row * Dn + c) = o;
}

// ---- generic 64x64-tile NN GEMM: C = A[M,K] @ B[K,N] (+bias)(+R)(gelu) ----
// Optional LN fused into B loads: B[k,n] -> (B-mean[k])*rstd[k]*gamma[n]+beta[n]
// epi: 0 plain, 1 += R (residual), 2 gelu
__global__ __launch_bounds__(256) void k_gemm64(
    const float* __restrict__ A, int lda, long sA,
    const float* __restrict__ Bm, int ldb, long sB,
    float* C, int ldc, long sC,
    const float* __restrict__ bias,
    const float* R,
    const float* __restrict__ nmean, const float* __restrict__ nrstd,
    int sN,
    const float* __restrict__ ngamma, const float* __restrict__ nbeta,
    int K, int epi) {
  int bz = blockIdx.z;
  A += (size_t)bz * sA;
  Bm += (size_t)bz * sB;
  C += (size_t)bz * sC;
  if (R) R += (size_t)bz * sC;
  const float* mn = nmean ? nmean + (size_t)bz * sN : nullptr;
  const float* rsp = nrstd ? nrstd + (size_t)bz * sN : nullptr;
  int m0 = blockIdx.y * 64, n0 = blockIdx.x * 64;
  int t = threadIdx.x;
  int tr = t >> 4, tc = t & 15;
  int ar = t >> 2, ak = (t & 3) * 4;
  int bk = t >> 4, bn = (t & 15) * 4;
  __shared__ float As[16][64];
  __shared__ float Bs[16][64];
  float acc[4][4] = {};
  for (int k0 = 0; k0 < K; k0 += 16) {
    f4 av = *(const f4*)(A + (size_t)(m0 + ar) * lda + k0 + ak);
    f4 bv = *(const f4*)(Bm + (size_t)(k0 + bk) * ldb + n0 + bn);
    if (mn) {
      float m = mn[k0 + bk], r = rsp[k0 + bk];
      bv.x = (bv.x - m) * r * ngamma[n0 + bn + 0] + nbeta[n0 + bn + 0];
      bv.y = (bv.y - m) * r * ngamma[n0 + bn + 1] + nbeta[n0 + bn + 1];
      bv.z = (bv.z - m) * r * ngamma[n0 + bn + 2] + nbeta[n0 + bn + 2];
      bv.w = (bv.w - m) * r * ngamma[n0 + bn + 3] + nbeta[n0 + bn + 3];
    }
    As[ak + 0][ar] = av.x; As[ak + 1][ar] = av.y;
    As[ak + 2][ar] = av.z; As[ak + 3][ar] = av.w;
    Bs[bk][bn + 0] = bv.x; Bs[bk][bn + 1] = bv.y;
    Bs[bk][bn + 2] = bv.z; Bs[bk][bn + 3] = bv.w;
    __syncthreads();
#pragma unroll
    for (int kk = 0; kk < 16; kk++) {
      f4 a = *(const f4*)&As[kk][tr * 4];
      f4 b = *(const f4*)&Bs[kk][tc * 4];
      acc[0][0] += a.x * b.x; acc[0][1] += a.x * b.y; acc[0][2] += a.x * b.z; acc[0][3] += a.x * b.w;
      acc[1][0] += a.y * b.x; acc[1][1] += a.y * b.y; acc[1][2] += a.y * b.z; acc[1][3] += a.y * b.w;
      acc[2][0] += a.z * b.x; acc[2][1] += a.z * b.y; acc[2][2] += a.z * b.z; acc[2][3] += a.z * b.w;
      acc[3][0] += a.w * b.x; acc[3][1] += a.w * b.y; acc[3][2] += a.w * b.z; acc[3][3] += a.w * b.w;
    }
    __syncthreads();
  }
#pragma unroll
  for (int i = 0; i < 4; i++) {
    int cm = m0 + tr * 4 + i;
    int cn = n0 + tc * 4;
    f4 v = make_float4(acc[i][0], acc[i][1], acc[i][2], acc[i][3]);
    if (bias) {
      v.x += bias[cn + 0]; v.y += bias[cn + 1];
      v.z += bias[cn + 2]; v.w += bias[cn + 3];
    }
    if (epi == 1) {
      const float* rr = R + (size_t)cm * ldc + cn;
      v.x += rr[0]; v.y += rr[1]; v.z += rr[2]; v.w += rr[3];
    } else if (epi == 2) {
      v.x = 0.5f * v.x * (1.f + erff(v.x * 0.70710678118654752f));
      v.y = 0.5f * v.y * (1.f + erff(v.y * 0.70710678118654752f));
      v.z = 0.5f * v.z * (1.f + erff(v.z * 0.70710678118654752f));
      v.w = 0.5f * v.w * (1.f + erff(v.w * 0.70710678118654752f));
    }
    *(f4*)(C + (size_t)cm * ldc + cn) = v;
  }
}

// ---- scores = SCALE * qw[b] @ ln(kv[b])^T (+part/slot bias, mask) ----
// A: qw [B][256=(h*16+q)][1024]; KV: raw kv [B][N][1024] with fused LN.
__global__ __launch_bounds__(256) void k_scores(
    const float* __restrict__ Aq, const float* __restrict__ KV,
    const float* __restrict__ mnb, const float* __restrict__ rsb,
    const float* __restrict__ g, const float* __restrict__ be,
    const void* tokmask, const void* palign, const int* __restrict__ slots,
    const float* __restrict__ pbias, const float* __restrict__ sbias,
    const int* __restrict__ flagp,
    float* __restrict__ Cc, int N, int maskon) {
  int b = blockIdx.z;
  const float* Ab = Aq + (size_t)b * 256 * Dn;
  const float* KVb = KV + (size_t)b * N * Dn;
  const float* mn = mnb + (size_t)b * N;
  const float* rs = rsb + (size_t)b * N;
  float* Cb = Cc + (size_t)b * 256 * N;
  int m0 = blockIdx.y * 64, n0 = blockIdx.x * 64;
  int t = threadIdx.x;
  int tr = t >> 4, tc = t & 15;
  int ar = t >> 2, ak = (t & 3) * 4;
  int bn = t >> 2, bk = (t & 3) * 4;
  __shared__ float As[16][64];
  __shared__ float Bs[16][64];
  float acc[4][4] = {};
  for (int k0 = 0; k0 < Dn; k0 += 16) {
    f4 av = *(const f4*)(Ab + (size_t)(m0 + ar) * Dn + k0 + ak);
    f4 bv = *(const f4*)(KVb + (size_t)(n0 + bn) * Dn + k0 + bk);
    float m = mn[n0 + bn], r = rs[n0 + bn];
    bv.x = (bv.x - m) * r * g[k0 + bk + 0] + be[k0 + bk + 0];
    bv.y = (bv.y - m) * r * g[k0 + bk + 1] + be[k0 + bk + 1];
    bv.z = (bv.z - m) * r * g[k0 + bk + 2] + be[k0 + bk + 2];
    bv.w = (bv.w - m) * r * g[k0 + bk + 3] + be[k0 + bk + 3];
    As[ak + 0][ar] = av.x; As[ak + 1][ar] = av.y;
    As[ak + 2][ar] = av.z; As[ak + 3][ar] = av.w;
    Bs[bk + 0][bn] = bv.x; Bs[bk + 1][bn] = bv.y;
    Bs[bk + 2][bn] = bv.z; Bs[bk + 3][bn] = bv.w;
    __syncthreads();
#pragma unroll
    for (int kk = 0; kk < 16; kk++) {
      f4 a = *(const f4*)&As[kk][tr * 4];
      f4 b2 = *(const f4*)&Bs[kk][tc * 4];
      acc[0][0] += a.x * b2.x; acc[0][1] += a.x * b2.y; acc[0][2] += a.x * b2.z; acc[0][3] += a.x * b2.w;
      acc[1][0] += a.y * b2.x; acc[1][1] += a.y * b2.y; acc[1][2] += a.y * b2.z; acc[1][3] += a.y * b2.w;
      acc[2][0] += a.z * b2.x; acc[2][1] += a.z * b2.y; acc[2][2] += a.z * b2.z; acc[2][3] += a.z * b2.w;
      acc[3][0] += a.w * b2.x; acc[3][1] += a.w * b2.y; acc[3][2] += a.w * b2.z; acc[3][3] += a.w * b2.w;
    }
    __syncthreads();
  }
  int m32 = *flagp;
#pragma unroll
  for (int i = 0; i < 4; i++) {
    int cm = m0 + tr * 4 + i;
    int hh = cm >> 4, qq = cm & 15;
#pragma unroll
    for (int j = 0; j < 4; j++) {
      int cn = n0 + tc * 4 + j;
      float v = acc[i][j] * SCALEf;
      if (maskon) {
        size_t pidx = (size_t)(b * Jn + qq) * N + cn;
        bool pm = m32 ? (((const int*)palign)[pidx] != 0)
                      : (((const unsigned char*)palign)[pidx] != 0);
        if (pm) v += pbias[hh];
        int sl = slots[(size_t)b * N + cn];
        sl = sl < 0 ? 0 : (sl > 3 ? 3 : sl);
        v += sbias[hh * 4 + sl];
        bool tm = m32 ? (((const int*)tokmask)[(size_t)b * N + cn] != 0)
                      : (((const unsigned char*)tokmask)[(size_t)b * N + cn] != 0);
        if (!tm) v = -FLT_MAX;
      }
      Cb[(size_t)cm * N + cn] = v;
    }
  }
}

// ---- in-place row softmax; ncols in {256, 2048} ----
__global__ __launch_bounds__(256) void k_softmax(float* __restrict__ x, int ncols) {
  int row = blockIdx.x, t = threadIdx.x;
  float* xr = x + (size_t)row * ncols;
  int cnt = ncols >> 8;
  float r[8];
  float mx = -FLT_MAX;
  for (int i = 0; i < cnt; i++) {
    r[i] = xr[t + (i << 8)];
    mx = fmaxf(mx, r[i]);
  }
  mx = block_max_bcast(mx);
  float sm = 0.f;
  for (int i = 0; i < cnt; i++) {
    r[i] = expf(r[i] - mx);
    sm += r[i];
  }
  sm = block_sum_bcast(sm);
  float inv = 1.f / sm;
  for (int i = 0; i < cnt; i++) xr[t + (i << 8)] = r[i] * inv;
}

// ---- self-attention over J=16 per (b,h); qkv packed [256][3072] ----
__global__ __launch_bounds__(256) void k_sa(const float* __restrict__ qkv,
                                            float* __restrict__ o) {
  int h = blockIdx.x, b = blockIdx.y, t = threadIdx.x;
  __shared__ float qs[16][68], ks[16][68], vs[16][68], ps[16][16];
  int rr = t >> 4, d4 = (t & 15) * 4;
  size_t base = (size_t)(b * Jn + rr) * 3072 + h * HDn + d4;
  *(f4*)&qs[rr][d4] = *(const f4*)(qkv + base);
  *(f4*)&ks[rr][d4] = *(const f4*)(qkv + base + 1024);
  *(f4*)&vs[rr][d4] = *(const f4*)(qkv + base + 2048);
  __syncthreads();
  int j1 = t >> 4, j2 = t & 15;
  float s = 0.f;
  for (int d = 0; d < 64; d++) s = fmaf(qs[j1][d], ks[j2][d], s);
  s *= SCALEf;
  float m = s;
#pragma unroll
  for (int oo = 8; oo; oo >>= 1) m = fmaxf(m, __shfl_xor(m, oo));
  float e = expf(s - m);
  float sm = e;
#pragma unroll
  for (int oo = 8; oo; oo >>= 1) sm += __shfl_xor(sm, oo);
  ps[j1][j2] = e / sm;
  __syncthreads();
  f4 acc = make_float4(0.f, 0.f, 0.f, 0.f);
#pragma unroll
  for (int k = 0; k < 16; k++) {
    float p = ps[j1][k];
    f4 v = *(const f4*)&vs[k][d4];
    acc.x += p * v.x; acc.y += p * v.y; acc.z += p * v.z; acc.w += p * v.w;
  }
  *(f4*)(o + (size_t)(b * Jn + j1) * Dn + h * HDn + d4) = acc;
}

// ---- qw[b, h*16+j, c] = sum_d q[(b,j), h*64+d] * W[c*ldw + wofs + h*64 + d] ----
__global__ __launch_bounds__(256) void k_qw(const float* __restrict__ q,
                                            const float* __restrict__ W,
                                            int ldw, int wofs, float* __restrict__ qw) {
  int b = blockIdx.z, h = blockIdx.y, c0 = blockIdx.x * 256;
  int t = threadIdx.x;
  __shared__ float qs[16][68];
  int rr = t >> 4, d4 = (t & 15) * 4;
  *(f4*)&qs[rr][d4] = *(const f4*)(q + (size_t)(b * Jn + rr) * Dn + h * HDn + d4);
  __syncthreads();
  int c = c0 + t;
  float acc[16] = {};
  const float* wr = W + (size_t)c * ldw + wofs + h * HDn;
  for (int d = 0; d < 64; d += 4) {
    f4 wv = *(const f4*)(wr + d);
#pragma unroll
    for (int j = 0; j < 16; j++) {
      acc[j] += wv.x * qs[j][d] + wv.y * qs[j][d + 1] + wv.z * qs[j][d + 2] + wv.w * qs[j][d + 3];
    }
  }
#pragma unroll
  for (int j = 0; j < 16; j++)
    qw[(size_t)(b * 256 + h * Jn + j) * Dn + c] = acc[j];
}

// ---- o[(b,j), h*64+d] = bias[h*64+d] + sum_c ctx[b, h*16+j, c]*W[c*ldw+wofs+h*64+d] ----
__global__ __launch_bounds__(256) void k_headout(
    const float* __restrict__ ctx, const float* __restrict__ W,
    int ldw, int wofs, const float* __restrict__ bias,
    float* __restrict__ o) {
  int h = blockIdx.x, b = blockIdx.y, t = threadIdx.x;
  __shared__ float cs[16][132];
  int j = t >> 4, d4 = (t & 15) * 4;
  f4 acc = make_float4(0.f, 0.f, 0.f, 0.f);
  for (int cc = 0; cc < 1024; cc += 128) {
    __syncthreads();
#pragma unroll
    for (int i = 0; i < 2; i++) {
      int f = t + i * 256;
      int row = f >> 5, c4 = (f & 31) * 4;
      *(f4*)&cs[row][c4] = *(const f4*)(ctx + (size_t)(b * 256 + h * Jn + row) * Dn + cc + c4);
    }
    __syncthreads();
    for (int c = 0; c < 128; c++) {
      f4 wv = *(const f4*)(W + (size_t)(cc + c) * ldw + wofs + h * HDn + d4);
      float a = cs[j][c];
      acc.x += a * wv.x; acc.y += a * wv.y; acc.z += a * wv.z; acc.w += a * wv.w;
    }
  }
  f4 bv = *(const f4*)(bias + h * HDn + d4);
  acc.x += bv.x; acc.y += bv.y; acc.z += bv.z; acc.w += bv.w;
  *(f4*)(o + (size_t)(b * Jn + j) * Dn + h * HDn + d4) = acc;
}

extern "C" void kernel_launch(void* const* d_in, const int* in_sizes, int n_in,
                              void* d_out, int out_size, void* d_ws, size_t ws_size,
                              hipStream_t stream) {
  (void)in_sizes; (void)n_in; (void)out_size; (void)ws_size;
  const float* h       = (const float*)d_in[0];
  const float* cond    = (const float*)d_in[1];
  const float* tkv     = (const float*)d_in[2];
  const void*  tmask   = d_in[3];
  const void*  palign  = d_in[4];
  const int*   slots   = (const int*)d_in[5];
  const float* skv     = (const float*)d_in[6];
  const float* film_w  = (const float*)d_in[7];
  const float* film_b  = (const float*)d_in[8];
  const float* ln_g    = (const float*)d_in[9];
  const float* ln_b    = (const float*)d_in[10];
  const float* sa_in_w = (const float*)d_in[11];
  const float* sa_in_b = (const float*)d_in[12];
  const float* sa_out_w= (const float*)d_in[13];
  const float* sa_out_b= (const float*)d_in[14];
  const float* cq_w    = (const float*)d_in[15];
  const float* cq_b    = (const float*)d_in[16];
  const float* ck_w    = (const float*)d_in[17];
  const float* cv_w    = (const float*)d_in[19];
  const float* cv_b    = (const float*)d_in[20];
  const float* co_w    = (const float*)d_in[21];
  const float* co_b    = (const float*)d_in[22];
  const float* sp_in_w = (const float*)d_in[23];
  const float* sp_in_b = (const float*)d_in[24];
  const float* sp_out_w= (const float*)d_in[25];
  const float* sp_out_b= (const float*)d_in[26];
  const float* pbias   = (const float*)d_in[27];
  const float* sbias   = (const float*)d_in[28];
  const float* fw1     = (const float*)d_in[29];
  const float* fb1     = (const float*)d_in[30];
  const float* fw2     = (const float*)d_in[31];
  const float* fb2     = (const float*)d_in[32];

  char* w = (char*)d_ws;
  size_t off = 0;
  auto carve = [&](size_t bytes) -> char* {
    char* p = w + off;
    off = (off + bytes + 255) & ~(size_t)255;
    return p;
  };
  int*   flag  = (int*)carve(256);
  float* stTm  = (float*)carve((size_t)Bn * Ln * 4);
  float* stTr  = (float*)carve((size_t)Bn * Ln * 4);
  float* stSm  = (float*)carve((size_t)Bn * Sn * 4);
  float* stSr  = (float*)carve((size_t)Bn * Sn * 4);
  float* film  = (float*)carve((size_t)Bn * 2048 * 4);
  float* xn    = (float*)carve((size_t)256 * Dn * 4);
  float* qbuf  = (float*)carve((size_t)256 * Dn * 4);
  float* obuf  = (float*)carve((size_t)256 * Dn * 4);
  float* A16   = (float*)carve((size_t)Bn * 256 * Dn * 4);   // qw then ctx (reused)
  float* scores= (float*)carve((size_t)Bn * 256 * Ln * 4);   // 32MB; also hosts qkv & ubuf
  // alias: qkv (3MB, used only during SA, before scores is written)
  float* qkv   = scores;
  // alias: ubuf (4MB, used only in FFN, after last read of scores)
  float* ubuf  = scores;
  float* hs = (float*)d_out;

  const float* g0 = ln_g + 0 * Dn; const float* b0 = ln_b + 0 * Dn;
  const float* g1 = ln_g + 1 * Dn; const float* b1 = ln_b + 1 * Dn;
  const float* g2 = ln_g + 2 * Dn; const float* b2 = ln_b + 2 * Dn;
  const float* g3 = ln_g + 3 * Dn; const float* b3 = ln_b + 3 * Dn;
  const float* g4 = ln_g + 4 * Dn; const float* b4 = ln_b + 4 * Dn;
  const float* g5 = ln_g + 5 * Dn; const float* b5 = ln_b + 5 * Dn;

  dim3 blk(256);
  const float* nul = nullptr;

  k_probe<<<1, blk, 0, stream>>>((const int*)tmask, flag);
  k_rowstats<<<Bn * Ln, blk, 0, stream>>>(tkv, stTm, stTr);
  k_rowstats<<<Bn * Sn, blk, 0, stream>>>(skv, stSm, stSr);
  k_film<<<dim3(8, Bn), blk, 0, stream>>>(cond, film_w, film_b, film);
  k_film_apply_ln<<<256, blk, 0, stream>>>(h, film, g0, b0, hs, xn);

  // --- self-attention ---
  k_gemm64<<<dim3(48, 4, 1), blk, 0, stream>>>(xn, Dn, 0, sa_in_w, 3072, 0, qkv, 3072, 0,
                                               sa_in_b, nullptr, nul, nul, 0, nul, nul, Dn, 0);
  k_sa<<<dim3(Hn, Bn), blk, 0, stream>>>(qkv, obuf);
  k_gemm64<<<dim3(16, 4, 1), blk, 0, stream>>>(obuf, Dn, 0, sa_out_w, Dn, 0, hs, Dn, 0,
                                               sa_out_b, hs, nul, nul, 0, nul, nul, Dn, 1);

  // --- masked token cross-attention (transpose trick) ---
  k_ln<<<256, blk, 0, stream>>>(hs, xn, g1, b1);
  k_gemm64<<<dim3(16, 4, 1), blk, 0, stream>>>(xn, Dn, 0, cq_w, Dn, 0, qbuf, Dn, 0,
                                               cq_b, nullptr, nul, nul, 0, nul, nul, Dn, 0);
  k_qw<<<dim3(4, Hn, Bn), blk, 0, stream>>>(qbuf, ck_w, Dn, 0, A16);
  k_scores<<<dim3(Ln / 64, 4, Bn), blk, 0, stream>>>(A16, tkv, stTm, stTr, g2, b2,
                                                     tmask, palign, slots, pbias, sbias, flag,
                                                     scores, Ln, 1);
  k_softmax<<<Bn * 256, blk, 0, stream>>>(scores, Ln);
  k_gemm64<<<dim3(16, 4, Bn), blk, 0, stream>>>(scores, Ln, (long)256 * Ln,
                                                tkv, Dn, (long)Ln * Dn,
                                                A16, Dn, (long)256 * Dn,
                                                nullptr, nullptr, stTm, stTr, Ln, g2, b2, Ln, 0);
  k_headout<<<dim3(Hn, Bn), blk, 0, stream>>>(A16, cv_w, Dn, 0, cv_b, obuf);
  k_gemm64<<<dim3(16, 4, 1), blk, 0, stream>>>(obuf, Dn, 0, co_w, Dn, 0, hs, Dn, 0,
                                               co_b, hs, nul, nul, 0, nul, nul, Dn, 1);

  // --- spatial cross-attention ---
  k_ln<<<256, blk, 0, stream>>>(hs, xn, g3, b3);
  k_gemm64<<<dim3(16, 4, 1), blk, 0, stream>>>(xn, Dn, 0, sp_in_w, 3072, 0, qbuf, Dn, 0,
                                               sp_in_b, nullptr, nul, nul, 0, nul, nul, Dn, 0);
  k_qw<<<dim3(4, Hn, Bn), blk, 0, stream>>>(qbuf, sp_in_w, 3072, Dn, A16);
  k_scores<<<dim3(Sn / 64, 4, Bn), blk, 0, stream>>>(A16, skv, stSm, stSr, g4, b4,
                                                     nullptr, nullptr, nullptr, nullptr, nullptr,
                                                     flag, scores, Sn, 0);
  k_softmax<<<Bn * 256, blk, 0, stream>>>(scores, Sn);
  k_gemm64<<<dim3(16, 4, Bn), blk, 0, stream>>>(scores, Sn, (long)256 * Sn,
                                                skv, Dn, (long)Sn * Dn,
                                                A16, Dn, (long)256 * Dn,
                                                nullptr, nullptr, stSm, stSr, Sn, g4, b4, Sn, 0);
  k_headout<<<dim3(Hn, Bn), blk, 0, stream>>>(A16, sp_in_w, 3072, 2048, sp_in_b + 2048, obuf);
  k_gemm64<<<dim3(16, 4, 1), blk, 0, stream>>>(obuf, Dn, 0, sp_out_w, Dn, 0, hs, Dn, 0,
                                               sp_out_b, hs, nul, nul, 0, nul, nul, Dn, 1);

  // --- FFN ---
  k_ln<<<256, blk, 0, stream>>>(hs, xn, g5, b5);
  k_gemm64<<<dim3(64, 4, 1), blk, 0, stream>>>(xn, Dn, 0, fw1, 4096, 0, ubuf, 4096, 0,
                                               fb1, nullptr, nul, nul, 0, nul, nul, Dn, 2);
  k_gemm64<<<dim3(16, 4, 1), blk, 0, stream>>>(ubuf, 4096, 0, fw2, Dn, 0, hs, Dn, 0,
                                               fb2, hs, nul, nul, 0, nul, nul, 4096, 1);
}

// Round 3
// 1403.082 us; speedup vs baseline: 1.5372x; 1.5372x over previous
//
#include <hip/hip_runtime.h>
#include <float.h>
#include <math.h>

// PoseHeadBlock, Round 3: all GEMMs on bf16 MFMA (16x16x32), f32 accumulate.
// Transpose trick for both cross-attentions; kv-LN fused into score B-staging;
// ctx reads pre-materialized LN+transposed bf16 kv (lnTt). Weights transposed
// to bf16 Bt[N][K] per call.

#define Bn 16
#define Jn 16
#define Ln 2048
#define Sn 256
#define Dn 1024
#define Hn 16
#define HDn 64

static const float EPSf = 1e-5f;
static const float SCALEf = 0.125f; // 1/sqrt(64)

typedef float4 f4;
typedef unsigned short u16;
typedef __attribute__((ext_vector_type(8))) short short8;
typedef __attribute__((ext_vector_type(4))) unsigned short us4;
typedef __attribute__((ext_vector_type(4))) float f32x4;

__device__ __forceinline__ u16 f2bf(float f) {
  unsigned u = __float_as_uint(f);
  unsigned r = (u + 0x7FFFu + ((u >> 16) & 1u)) >> 16;
  return (u16)r;
}

__device__ __forceinline__ float wave_sum(float v) {
#pragma unroll
  for (int o = 32; o; o >>= 1) v += __shfl_xor(v, o);
  return v;
}
__device__ __forceinline__ float wave_max(float v) {
#pragma unroll
  for (int o = 32; o; o >>= 1) v = fmaxf(v, __shfl_xor(v, o));
  return v;
}
__device__ __forceinline__ void block_reduce2(float& a, float& b) {
  __shared__ float la[4], lb[4];
  a = wave_sum(a); b = wave_sum(b);
  int t = threadIdx.x, w = t >> 6;
  __syncthreads();
  if ((t & 63) == 0) { la[w] = a; lb[w] = b; }
  __syncthreads();
  a = la[0] + la[1] + la[2] + la[3];
  b = lb[0] + lb[1] + lb[2] + lb[3];
}
__device__ __forceinline__ float block_max_bcast(float v) {
  __shared__ float lm[4];
  v = wave_max(v);
  int t = threadIdx.x;
  __syncthreads();
  if ((t & 63) == 0) lm[t >> 6] = v;
  __syncthreads();
  return fmaxf(fmaxf(lm[0], lm[1]), fmaxf(lm[2], lm[3]));
}
__device__ __forceinline__ float block_sum_bcast(float v) {
  __shared__ float ls[4];
  v = wave_sum(v);
  int t = threadIdx.x;
  __syncthreads();
  if ((t & 63) == 0) ls[t >> 6] = v;
  __syncthreads();
  return ls[0] + ls[1] + ls[2] + ls[3];
}

// ---- mask dtype probe: flag=1 -> int32 bools, 0 -> uint8 bools ----
__global__ __launch_bounds__(256) void k_probe(const int* __restrict__ tm, int* flag) {
  __shared__ int bad;
  int t = threadIdx.x;
  if (t == 0) bad = 0;
  __syncthreads();
  int loc = 0;
  for (int i = t; i < 4096; i += 256) {
    unsigned v = (unsigned)tm[i];
    if (v > 1u) loc = 1;
  }
  if (loc) bad = 1;
  __syncthreads();
  if (t == 0) *flag = bad ? 0 : 1;
}

// ---- per-row mean/rstd over D=1024 ----
__global__ __launch_bounds__(256) void k_rowstats(const float* __restrict__ x,
                                                  float* __restrict__ mean,
                                                  float* __restrict__ rstd) {
  int row = blockIdx.x, t = threadIdx.x;
  f4 v = *(const f4*)(x + (size_t)row * Dn + t * 4);
  float s = v.x + v.y + v.z + v.w;
  float s2 = v.x * v.x + v.y * v.y + v.z * v.z + v.w * v.w;
  block_reduce2(s, s2);
  if (t == 0) {
    float m = s * (1.f / Dn);
    float var = s2 * (1.f / Dn) - m * m;
    if (var < 0.f) var = 0.f;
    mean[row] = m;
    rstd[row] = rsqrtf(var + EPSf);
  }
}

// ---- LN + transpose: out[b][d][l] bf16 = LN(kv[b][l][d]) ----
__global__ __launch_bounds__(256) void k_lnt(const float* __restrict__ kv,
                                             const float* __restrict__ mean,
                                             const float* __restrict__ rstd,
                                             const float* __restrict__ g,
                                             const float* __restrict__ be,
                                             u16* __restrict__ out, int Lkv) {
  int b = blockIdx.z, d0 = blockIdx.x * 32, l0 = blockIdx.y * 32;
  __shared__ float tile[32][33];
  int t = threadIdx.x;
  int r = t >> 3, c4 = (t & 7) * 4;
  const float* kvb = kv + (size_t)b * Lkv * Dn;
  f4 v = *(const f4*)(kvb + (size_t)(l0 + r) * Dn + d0 + c4);
  float m = mean[(size_t)b * Lkv + l0 + r], rs = rstd[(size_t)b * Lkv + l0 + r];
  tile[r][c4 + 0] = (v.x - m) * rs * g[d0 + c4 + 0] + be[d0 + c4 + 0];
  tile[r][c4 + 1] = (v.y - m) * rs * g[d0 + c4 + 1] + be[d0 + c4 + 1];
  tile[r][c4 + 2] = (v.z - m) * rs * g[d0 + c4 + 2] + be[d0 + c4 + 2];
  tile[r][c4 + 3] = (v.w - m) * rs * g[d0 + c4 + 3] + be[d0 + c4 + 3];
  __syncthreads();
  int dr = t >> 3, l4 = (t & 7) * 4;
  us4 o;
  o.x = f2bf(tile[l4 + 0][dr]);
  o.y = f2bf(tile[l4 + 1][dr]);
  o.z = f2bf(tile[l4 + 2][dr]);
  o.w = f2bf(tile[l4 + 3][dr]);
  *(us4*)(out + (size_t)b * Dn * Lkv + (size_t)(d0 + dr) * Lkv + l0 + l4) = o;
}

// ---- weight f32 [K x ldw] (cols nofs..nofs+Nt) -> bf16 Bt[Nt][K] ----
__global__ __launch_bounds__(256) void k_wt(const float* __restrict__ W, int ldw,
                                            int nofs, int K, u16* __restrict__ out) {
  int n0 = blockIdx.x * 32, k0 = blockIdx.y * 32;
  __shared__ float tile[32][33];
  int t = threadIdx.x;
  int r = t >> 3, c4 = (t & 7) * 4; // r = k-row, c = n-col
  f4 v = *(const f4*)(W + (size_t)(k0 + r) * ldw + nofs + n0 + c4);
  tile[r][c4 + 0] = v.x; tile[r][c4 + 1] = v.y;
  tile[r][c4 + 2] = v.z; tile[r][c4 + 3] = v.w;
  __syncthreads();
  int nr = t >> 3, k4 = (t & 7) * 4;
  us4 o;
  o.x = f2bf(tile[k4 + 0][nr]);
  o.y = f2bf(tile[k4 + 1][nr]);
  o.z = f2bf(tile[k4 + 2][nr]);
  o.w = f2bf(tile[k4 + 3][nr]);
  *(us4*)(out + (size_t)(n0 + nr) * K + k0 + k4) = o;
}

// ---- film = cond @ film_w + film_b ; [B,2048] f32 ----
__global__ __launch_bounds__(256) void k_film(const float* __restrict__ cond,
                                              const float* __restrict__ fw,
                                              const float* __restrict__ fb,
                                              float* __restrict__ film) {
  int b = blockIdx.y, t = threadIdx.x;
  int n = blockIdx.x * 256 + t;
  __shared__ float cs[512];
  cs[t] = cond[b * 512 + t];
  cs[t + 256] = cond[b * 512 + 256 + t];
  __syncthreads();
  float acc = fb[n];
  for (int k = 0; k < 512; k++) acc = fmaf(cs[k], fw[(size_t)k * 2048 + n], acc);
  film[b * 2048 + n] = acc;
}

// ---- h' = h*(1+s)+sh -> hs f32 ; xn = LN(h') bf16 ----
__global__ __launch_bounds__(256) void k_film_apply_ln(
    const float* __restrict__ h, const float* __restrict__ film,
    const float* __restrict__ g, const float* __restrict__ be,
    float* __restrict__ hs, u16* __restrict__ xn) {
  int row = blockIdx.x, t = threadIdx.x, b = row >> 4;
  int c = t * 4;
  f4 hv = *(const f4*)(h + (size_t)row * Dn + c);
  f4 sv = *(const f4*)(film + (size_t)b * 2048 + c);
  f4 shv = *(const f4*)(film + (size_t)b * 2048 + 1024 + c);
  f4 v;
  v.x = hv.x * (1.f + sv.x) + shv.x;
  v.y = hv.y * (1.f + sv.y) + shv.y;
  v.z = hv.z * (1.f + sv.z) + shv.z;
  v.w = hv.w * (1.f + sv.w) + shv.w;
  *(f4*)(hs + (size_t)row * Dn + c) = v;
  float s = v.x + v.y + v.z + v.w;
  float s2 = v.x * v.x + v.y * v.y + v.z * v.z + v.w * v.w;
  block_reduce2(s, s2);
  float m = s * (1.f / Dn);
  float var = fmaxf(s2 * (1.f / Dn) - m * m, 0.f);
  float rs = rsqrtf(var + EPSf);
  us4 o;
  o.x = f2bf((v.x - m) * rs * g[c + 0] + be[c + 0]);
  o.y = f2bf((v.y - m) * rs * g[c + 1] + be[c + 1]);
  o.z = f2bf((v.z - m) * rs * g[c + 2] + be[c + 2]);
  o.w = f2bf((v.w - m) * rs * g[c + 3] + be[c + 3]);
  *(us4*)(xn + (size_t)row * Dn + c) = o;
}

// ---- row LN f32 -> bf16 ----
__global__ __launch_bounds__(256) void k_ln(const float* __restrict__ x,
                                            u16* __restrict__ y,
                                            const float* __restrict__ g,
                                            const float* __restrict__ be) {
  int row = blockIdx.x, t = threadIdx.x;
  int c = t * 4;
  f4 v = *(const f4*)(x + (size_t)row * Dn + c);
  float s = v.x + v.y + v.z + v.w;
  float s2 = v.x * v.x + v.y * v.y + v.z * v.z + v.w * v.w;
  block_reduce2(s, s2);
  float m = s * (1.f / Dn);
  float var = fmaxf(s2 * (1.f / Dn) - m * m, 0.f);
  float rs = rsqrtf(var + EPSf);
  us4 o;
  o.x = f2bf((v.x - m) * rs * g[c + 0] + be[c + 0]);
  o.y = f2bf((v.y - m) * rs * g[c + 1] + be[c + 1]);
  o.z = f2bf((v.z - m) * rs * g[c + 2] + be[c + 2]);
  o.w = f2bf((v.w - m) * rs * g[c + 3] + be[c + 3]);
  *(us4*)(y + (size_t)row * Dn + c) = o;
}

// ============ unified MFMA GEMM: C[M=256][N] = A(bf16)[M][K] @ Bt[N][K]^T ============
// bmode: 0 = Bt bf16; 1 = B from f32 KV rows with fused LN (mean/rstd per n-row,
//        gamma/beta per k-col), cvt to bf16.
// epi:   0 f32 out (+bias); 1 f32 out +bias+resid; 2 bf16 out +bias+gelu;
//        3 f32 out token-scores (scale, part/slot bias, token mask);
//        4 f32 out *SCALE.
#define LSTR 72
__global__ __launch_bounds__(256) void k_gemm_mfma(
    const u16* __restrict__ A, int lda, long sA,
    const void* __restrict__ Bsrc, int ldb, long sB,
    float* __restrict__ C, int ldc, long sC,
    u16* __restrict__ Cb,
    const float* __restrict__ bias,
    const float* __restrict__ resid,
    const float* __restrict__ nmean, const float* __restrict__ nrstd, int sStat,
    const float* __restrict__ ngamma, const float* __restrict__ nbeta,
    int K, int bmode, int epi,
    const void* tokmask, const void* palign, const int* __restrict__ slots,
    const float* __restrict__ pbias, const float* __restrict__ sbias,
    const int* __restrict__ flagp, int Nkv) {
  int bz = blockIdx.z;
  A += (size_t)bz * sA;
  const u16* Bt = (const u16*)Bsrc + (bmode == 0 ? (size_t)bz * sB : 0);
  const float* KV = (const float*)Bsrc + (bmode == 1 ? (size_t)bz * sB : 0);
  C += (size_t)bz * sC;
  if (Cb) Cb += (size_t)bz * sC;
  if (resid) resid += (size_t)bz * sC;
  const float* mn = nmean ? nmean + (size_t)bz * sStat : nullptr;
  const float* rsd = nrstd ? nrstd + (size_t)bz * sStat : nullptr;

  __shared__ u16 As[128 * LSTR];
  __shared__ u16 Bs[128 * LSTR];
  int t = threadIdx.x;
  int m0 = blockIdx.y * 128, n0 = blockIdx.x * 128;
  int w = t >> 6, l = t & 63;
  int wr = (w >> 1) * 64, wc = (w & 1) * 64;
  int lr = l & 15, lg = l >> 4;

  f32x4 acc[4][4];
#pragma unroll
  for (int m = 0; m < 4; m++)
#pragma unroll
    for (int n = 0; n < 4; n++) acc[m][n] = (f32x4){0.f, 0.f, 0.f, 0.f};

  for (int k0 = 0; k0 < K; k0 += 64) {
#pragma unroll
    for (int i = 0; i < 4; i++) {
      int idx = i * 256 + t;
      int r = idx >> 3, c = (idx & 7) * 8;
      *(short8*)&As[r * LSTR + c] =
          *(const short8*)(const void*)(A + (size_t)(m0 + r) * lda + k0 + c);
    }
    if (bmode == 0) {
#pragma unroll
      for (int i = 0; i < 4; i++) {
        int idx = i * 256 + t;
        int r = idx >> 3, c = (idx & 7) * 8;
        *(short8*)&Bs[r * LSTR + c] =
            *(const short8*)(const void*)(Bt + (size_t)(n0 + r) * ldb + k0 + c);
      }
    } else {
#pragma unroll
      for (int i = 0; i < 8; i++) {
        int idx = i * 256 + t;
        int r = idx >> 4, c = (idx & 15) * 4;
        f4 v = *(const f4*)(KV + (size_t)(n0 + r) * ldb + k0 + c);
        float m = mn[n0 + r], rs = rsd[n0 + r];
        us4 o;
        o.x = f2bf((v.x - m) * rs * ngamma[k0 + c + 0] + nbeta[k0 + c + 0]);
        o.y = f2bf((v.y - m) * rs * ngamma[k0 + c + 1] + nbeta[k0 + c + 1]);
        o.z = f2bf((v.z - m) * rs * ngamma[k0 + c + 2] + nbeta[k0 + c + 2]);
        o.w = f2bf((v.w - m) * rs * ngamma[k0 + c + 3] + nbeta[k0 + c + 3]);
        *(us4*)&Bs[r * LSTR + c] = o;
      }
    }
    __syncthreads();
#pragma unroll
    for (int ks = 0; ks < 2; ks++) {
      short8 a[4], b[4];
#pragma unroll
      for (int m = 0; m < 4; m++)
        a[m] = *(const short8*)&As[(wr + m * 16 + lr) * LSTR + ks * 32 + lg * 8];
#pragma unroll
      for (int n = 0; n < 4; n++)
        b[n] = *(const short8*)&Bs[(wc + n * 16 + lr) * LSTR + ks * 32 + lg * 8];
#pragma unroll
      for (int m = 0; m < 4; m++)
#pragma unroll
        for (int n = 0; n < 4; n++)
          acc[m][n] = __builtin_amdgcn_mfma_f32_16x16x32_bf16(a[m], b[n], acc[m][n], 0, 0, 0);
    }
    __syncthreads();
  }

  int m32 = (epi == 3) ? *flagp : 0;
#pragma unroll
  for (int m = 0; m < 4; m++) {
#pragma unroll
    for (int n = 0; n < 4; n++) {
#pragma unroll
      for (int i = 0; i < 4; i++) {
        int gr = m0 + wr + m * 16 + lg * 4 + i;
        int gc = n0 + wc + n * 16 + lr;
        float v = acc[m][n][i];
        if (bias) v += bias[gc];
        if (epi == 1) v += resid[(size_t)gr * ldc + gc];
        if (epi == 2) {
          v = 0.5f * v * (1.f + erff(v * 0.70710678118654752f));
          Cb[(size_t)gr * ldc + gc] = f2bf(v);
          continue;
        }
        if (epi == 3) {
          v *= SCALEf;
          int hh = gr >> 4, qq = gr & 15;
          size_t pidx = (size_t)(bz * Jn + qq) * Nkv + gc;
          bool pm = m32 ? (((const int*)palign)[pidx] != 0)
                        : (((const unsigned char*)palign)[pidx] != 0);
          if (pm) v += pbias[hh];
          int sl = slots[(size_t)bz * Nkv + gc];
          sl = sl < 0 ? 0 : (sl > 3 ? 3 : sl);
          v += sbias[hh * 4 + sl];
          bool tm = m32 ? (((const int*)tokmask)[(size_t)bz * Nkv + gc] != 0)
                        : (((const unsigned char*)tokmask)[(size_t)bz * Nkv + gc] != 0);
          if (!tm) v = -FLT_MAX;
        } else if (epi == 4) {
          v *= SCALEf;
        }
        C[(size_t)gr * ldc + gc] = v;
      }
    }
  }
}

// ---- row softmax f32 in -> bf16 out; ncols in {256, 2048} ----
__global__ __launch_bounds__(256) void k_softmax(const float* __restrict__ x,
                                                 u16* __restrict__ p, int ncols) {
  int row = blockIdx.x, t = threadIdx.x;
  const float* xr = x + (size_t)row * ncols;
  u16* pr = p + (size_t)row * ncols;
  int cnt = ncols >> 8;
  float r[8];
  float mx = -FLT_MAX;
  for (int i = 0; i < cnt; i++) {
    r[i] = xr[t + (i << 8)];
    mx = fmaxf(mx, r[i]);
  }
  mx = block_max_bcast(mx);
  float sm = 0.f;
  for (int i = 0; i < cnt; i++) {
    r[i] = expf(r[i] - mx);
    sm += r[i];
  }
  sm = block_sum_bcast(sm);
  float inv = 1.f / sm;
  for (int i = 0; i < cnt; i++) pr[t + (i << 8)] = f2bf(r[i] * inv);
}

// ---- self-attention over J=16 per (b,h); qkv f32 [256][3072]; out bf16 ----
__global__ __launch_bounds__(256) void k_sa(const float* __restrict__ qkv,
                                            u16* __restrict__ o) {
  int h = blockIdx.x, b = blockIdx.y, t = threadIdx.x;
  __shared__ float qs[16][68], ks[16][68], vs[16][68], ps[16][16];
  int rr = t >> 4, d4 = (t & 15) * 4;
  size_t base = (size_t)(b * Jn + rr) * 3072 + h * HDn + d4;
  *(f4*)&qs[rr][d4] = *(const f4*)(qkv + base);
  *(f4*)&ks[rr][d4] = *(const f4*)(qkv + base + 1024);
  *(f4*)&vs[rr][d4] = *(const f4*)(qkv + base + 2048);
  __syncthreads();
  int j1 = t >> 4, j2 = t & 15;
  float s = 0.f;
  for (int d = 0; d < 64; d++) s = fmaf(qs[j1][d], ks[j2][d], s);
  s *= SCALEf;
  float m = s;
#pragma unroll
  for (int oo = 8; oo; oo >>= 1) m = fmaxf(m, __shfl_xor(m, oo));
  float e = expf(s - m);
  float sm = e;
#pragma unroll
  for (int oo = 8; oo; oo >>= 1) sm += __shfl_xor(sm, oo);
  ps[j1][j2] = e / sm;
  __syncthreads();
  f4 acc = make_float4(0.f, 0.f, 0.f, 0.f);
#pragma unroll
  for (int k = 0; k < 16; k++) {
    float p = ps[j1][k];
    f4 v = *(const f4*)&vs[k][d4];
    acc.x += p * v.x; acc.y += p * v.y; acc.z += p * v.z; acc.w += p * v.w;
  }
  us4 ov;
  ov.x = f2bf(acc.x); ov.y = f2bf(acc.y); ov.z = f2bf(acc.z); ov.w = f2bf(acc.w);
  *(us4*)(o + (size_t)(b * Jn + j1) * Dn + h * HDn + d4) = ov;
}

// ---- qw[b, h*16+j, c] = sum_d q[(b,j), h*64+d] * W[c*ldw + wofs + h*64 + d]; bf16 out ----
__global__ __launch_bounds__(256) void k_qw(const float* __restrict__ q,
                                            const float* __restrict__ W,
                                            int ldw, int wofs, u16* __restrict__ qw) {
  int b = blockIdx.z, h = blockIdx.y, c0 = blockIdx.x * 256;
  int t = threadIdx.x;
  __shared__ float qs[16][68];
  int rr = t >> 4, d4 = (t & 15) * 4;
  *(f4*)&qs[rr][d4] = *(const f4*)(q + (size_t)(b * Jn + rr) * Dn + h * HDn + d4);
  __syncthreads();
  int c = c0 + t;
  float acc[16] = {};
  const float* wr = W + (size_t)c * ldw + wofs + h * HDn;
  for (int d = 0; d < 64; d += 4) {
    f4 wv = *(const f4*)(wr + d);
#pragma unroll
    for (int j = 0; j < 16; j++) {
      acc[j] += wv.x * qs[j][d] + wv.y * qs[j][d + 1] + wv.z * qs[j][d + 2] + wv.w * qs[j][d + 3];
    }
  }
#pragma unroll
  for (int j = 0; j < 16; j++)
    qw[(size_t)(b * 256 + h * Jn + j) * Dn + c] = f2bf(acc[j]);
}

// ---- o[(b,j), h*64+d] = bias + sum_c ctx[b,h*16+j,c]*W[c*ldw+wofs+h*64+d]; bf16 out ----
__global__ __launch_bounds__(256) void k_headout(
    const float* __restrict__ ctx, const float* __restrict__ W,
    int ldw, int wofs, const float* __restrict__ bias, u16* __restrict__ o) {
  int h = blockIdx.x, b = blockIdx.y, t = threadIdx.x;
  __shared__ float cs[16][132];
  int j = t >> 4, d4 = (t & 15) * 4;
  f4 acc = make_float4(0.f, 0.f, 0.f, 0.f);
  for (int cc = 0; cc < 1024; cc += 128) {
    __syncthreads();
#pragma unroll
    for (int i = 0; i < 2; i++) {
      int f = t + i * 256;
      int row = f >> 5, c4 = (f & 31) * 4;
      *(f4*)&cs[row][c4] = *(const f4*)(ctx + (size_t)(b * 256 + h * Jn + row) * Dn + cc + c4);
    }
    __syncthreads();
    for (int c = 0; c < 128; c++) {
      f4 wv = *(const f4*)(W + (size_t)(cc + c) * ldw + wofs + h * HDn + d4);
      float a = cs[j][c];
      acc.x += a * wv.x; acc.y += a * wv.y; acc.z += a * wv.z; acc.w += a * wv.w;
    }
  }
  f4 bv = *(const f4*)(bias + h * HDn + d4);
  us4 ov;
  ov.x = f2bf(acc.x + bv.x); ov.y = f2bf(acc.y + bv.y);
  ov.z = f2bf(acc.z + bv.z); ov.w = f2bf(acc.w + bv.w);
  *(us4*)(o + (size_t)(b * Jn + j) * Dn + h * HDn + d4) = ov;
}

extern "C" void kernel_launch(void* const* d_in, const int* in_sizes, int n_in,
                              void* d_out, int out_size, void* d_ws, size_t ws_size,
                              hipStream_t stream) {
  (void)in_sizes; (void)n_in; (void)out_size; (void)ws_size;
  const float* h       = (const float*)d_in[0];
  const float* cond    = (const float*)d_in[1];
  const float* tkv     = (const float*)d_in[2];
  const void*  tmask   = d_in[3];
  const void*  palign  = d_in[4];
  const int*   slots   = (const int*)d_in[5];
  const float* skv     = (const float*)d_in[6];
  const float* film_w  = (const float*)d_in[7];
  const float* film_b  = (const float*)d_in[8];
  const float* ln_g    = (const float*)d_in[9];
  const float* ln_b    = (const float*)d_in[10];
  const float* sa_in_w = (const float*)d_in[11];
  const float* sa_in_b = (const float*)d_in[12];
  const float* sa_out_w= (const float*)d_in[13];
  const float* sa_out_b= (const float*)d_in[14];
  const float* cq_w    = (const float*)d_in[15];
  const float* cq_b    = (const float*)d_in[16];
  const float* cv_w    = (const float*)d_in[19];
  const float* cv_b    = (const float*)d_in[20];
  const float* co_w    = (const float*)d_in[21];
  const float* co_b    = (const float*)d_in[22];
  const float* sp_in_w = (const float*)d_in[23];
  const float* sp_in_b = (const float*)d_in[24];
  const float* sp_out_w= (const float*)d_in[25];
  const float* sp_out_b= (const float*)d_in[26];
  const float* pbias   = (const float*)d_in[27];
  const float* sbias   = (const float*)d_in[28];
  const float* fw1     = (const float*)d_in[29];
  const float* fb1     = (const float*)d_in[30];
  const float* fw2     = (const float*)d_in[31];
  const float* fb2     = (const float*)d_in[32];
  const float* ck_w    = (const float*)d_in[17];

  char* wsp = (char*)d_ws;
  size_t off = 0;
  auto carve = [&](size_t bytes) -> char* {
    char* p = wsp + off;
    off = (off + bytes + 255) & ~(size_t)255;
    return p;
  };
  int*   flag  = (int*)carve(256);
  float* stTm  = (float*)carve((size_t)Bn * Ln * 4);
  float* stTr  = (float*)carve((size_t)Bn * Ln * 4);
  float* stSm  = (float*)carve((size_t)Bn * Sn * 4);
  float* stSr  = (float*)carve((size_t)Bn * Sn * 4);
  float* film  = (float*)carve((size_t)Bn * 2048 * 4);
  u16*   xn    = (u16*)carve((size_t)256 * Dn * 2);
  float* qbuf  = (float*)carve((size_t)256 * Dn * 4);
  u16*   obuf  = (u16*)carve((size_t)256 * Dn * 2);
  u16*   qw    = (u16*)carve((size_t)Bn * 256 * Dn * 2);
  u16*   Pb    = (u16*)carve((size_t)Bn * 256 * Ln * 2);
  float* big   = (float*)carve((size_t)Bn * 256 * Ln * 4);  // scores / qkv / A16 / ubuf
  u16*   lnTt  = (u16*)carve((size_t)Bn * Dn * Ln * 2);
  u16*   lnSt  = (u16*)carve((size_t)Bn * Dn * Sn * 2);
  u16*   wsa   = (u16*)carve((size_t)3072 * Dn * 2);
  u16*   wso   = (u16*)carve((size_t)Dn * Dn * 2);
  u16*   wcq   = (u16*)carve((size_t)Dn * Dn * 2);
  u16*   wco   = (u16*)carve((size_t)Dn * Dn * 2);
  u16*   wspq  = (u16*)carve((size_t)Dn * Dn * 2);
  u16*   wspo  = (u16*)carve((size_t)Dn * Dn * 2);
  u16*   wf1   = (u16*)carve((size_t)4096 * Dn * 2);
  u16*   wf2   = (u16*)carve((size_t)Dn * 4096 * 2);

  float* qkv  = big;          // f32 [256][3072], SA only
  float* scores = big;        // f32 [B][256][L]
  float* A16  = big;          // f32 [B][256][1024] ctx out (after softmax consumed scores)
  u16*   ubuf = (u16*)big;    // bf16 [256][4096], FFN only
  float* hs = (float*)d_out;

  const float* g0 = ln_g + 0 * Dn; const float* b0 = ln_b + 0 * Dn;
  const float* g1 = ln_g + 1 * Dn; const float* b1 = ln_b + 1 * Dn;
  const float* g2 = ln_g + 2 * Dn; const float* b2 = ln_b + 2 * Dn;
  const float* g3 = ln_g + 3 * Dn; const float* b3 = ln_b + 3 * Dn;
  const float* g4 = ln_g + 4 * Dn; const float* b4 = ln_b + 4 * Dn;
  const float* g5 = ln_g + 5 * Dn; const float* b5 = ln_b + 5 * Dn;

  dim3 blk(256);
  const float* nulf = nullptr;
  u16* nulb = nullptr;

  // ---- prep ----
  k_probe<<<1, blk, 0, stream>>>((const int*)tmask, flag);
  k_rowstats<<<Bn * Ln, blk, 0, stream>>>(tkv, stTm, stTr);
  k_rowstats<<<Bn * Sn, blk, 0, stream>>>(skv, stSm, stSr);
  k_lnt<<<dim3(32, 64, Bn), blk, 0, stream>>>(tkv, stTm, stTr, g2, b2, lnTt, Ln);
  k_lnt<<<dim3(32, 8, Bn), blk, 0, stream>>>(skv, stSm, stSr, g4, b4, lnSt, Sn);
  k_wt<<<dim3(96, 32), blk, 0, stream>>>(sa_in_w, 3072, 0, Dn, wsa);
  k_wt<<<dim3(32, 32), blk, 0, stream>>>(sa_out_w, 1024, 0, Dn, wso);
  k_wt<<<dim3(32, 32), blk, 0, stream>>>(cq_w, 1024, 0, Dn, wcq);
  k_wt<<<dim3(32, 32), blk, 0, stream>>>(co_w, 1024, 0, Dn, wco);
  k_wt<<<dim3(32, 32), blk, 0, stream>>>(sp_in_w, 3072, 0, Dn, wspq);
  k_wt<<<dim3(32, 32), blk, 0, stream>>>(sp_out_w, 1024, 0, Dn, wspo);
  k_wt<<<dim3(128, 32), blk, 0, stream>>>(fw1, 4096, 0, Dn, wf1);
  k_wt<<<dim3(32, 128), blk, 0, stream>>>(fw2, 1024, 0, 4096, wf2);
  k_film<<<dim3(8, Bn), blk, 0, stream>>>(cond, film_w, film_b, film);
  k_film_apply_ln<<<256, blk, 0, stream>>>(h, film, g0, b0, hs, xn);

  // ---- self-attention ----
  k_gemm_mfma<<<dim3(24, 2, 1), blk, 0, stream>>>(
      xn, Dn, 0, wsa, Dn, 0, qkv, 3072, 0, nulb, sa_in_b, nulf,
      nulf, nulf, 0, nulf, nulf, Dn, 0, 0,
      nullptr, nullptr, nullptr, nulf, nulf, nullptr, 0);
  k_sa<<<dim3(Hn, Bn), blk, 0, stream>>>(qkv, obuf);
  k_gemm_mfma<<<dim3(8, 2, 1), blk, 0, stream>>>(
      obuf, Dn, 0, wso, Dn, 0, hs, Dn, 0, nulb, sa_out_b, hs,
      nulf, nulf, 0, nulf, nulf, Dn, 0, 1,
      nullptr, nullptr, nullptr, nulf, nulf, nullptr, 0);

  // ---- masked token cross-attention (transpose trick) ----
  k_ln<<<256, blk, 0, stream>>>(hs, xn, g1, b1);
  k_gemm_mfma<<<dim3(8, 2, 1), blk, 0, stream>>>(
      xn, Dn, 0, wcq, Dn, 0, qbuf, Dn, 0, nulb, cq_b, nulf,
      nulf, nulf, 0, nulf, nulf, Dn, 0, 0,
      nullptr, nullptr, nullptr, nulf, nulf, nullptr, 0);
  k_qw<<<dim3(4, Hn, Bn), blk, 0, stream>>>(qbuf, ck_w, Dn, 0, qw);
  k_gemm_mfma<<<dim3(16, 2, Bn), blk, 0, stream>>>(
      qw, Dn, (long)256 * Dn, tkv, Dn, (long)Ln * Dn,
      scores, Ln, (long)256 * Ln, nulb, nulf, nulf,
      stTm, stTr, Ln, g2, b2, Dn, 1, 3,
      tmask, palign, slots, pbias, sbias, flag, Ln);
  k_softmax<<<Bn * 256, blk, 0, stream>>>(scores, Pb, Ln);
  k_gemm_mfma<<<dim3(8, 2, Bn), blk, 0, stream>>>(
      Pb, Ln, (long)256 * Ln, lnTt, Ln, (long)Dn * Ln,
      A16, Dn, (long)256 * Dn, nulb, nulf, nulf,
      nulf, nulf, 0, nulf, nulf, Ln, 0, 0,
      nullptr, nullptr, nullptr, nulf, nulf, nullptr, 0);
  k_headout<<<dim3(Hn, Bn), blk, 0, stream>>>(A16, cv_w, Dn, 0, cv_b, obuf);
  k_gemm_mfma<<<dim3(8, 2, 1), blk, 0, stream>>>(
      obuf, Dn, 0, wco, Dn, 0, hs, Dn, 0, nulb, co_b, hs,
      nulf, nulf, 0, nulf, nulf, Dn, 0, 1,
      nullptr, nullptr, nullptr, nulf, nulf, nullptr, 0);

  // ---- spatial cross-attention ----
  k_ln<<<256, blk, 0, stream>>>(hs, xn, g3, b3);
  k_gemm_mfma<<<dim3(8, 2, 1), blk, 0, stream>>>(
      xn, Dn, 0, wspq, Dn, 0, qbuf, Dn, 0, nulb, sp_in_b, nulf,
      nulf, nulf, 0, nulf, nulf, Dn, 0, 0,
      nullptr, nullptr, nullptr, nulf, nulf, nullptr, 0);
  k_qw<<<dim3(4, Hn, Bn), blk, 0, stream>>>(qbuf, sp_in_w, 3072, 1024, qw);
  k_gemm_mfma<<<dim3(2, 2, Bn), blk, 0, stream>>>(
      qw, Dn, (long)256 * Dn, skv, Dn, (long)Sn * Dn,
      scores, Sn, (long)256 * Sn, nulb, nulf, nulf,
      stSm, stSr, Sn, g4, b4, Dn, 1, 4,
      nullptr, nullptr, nullptr, nulf, nulf, nullptr, Sn);
  k_softmax<<<Bn * 256, blk, 0, stream>>>(scores, Pb, Sn);
  k_gemm_mfma<<<dim3(8, 2, Bn), blk, 0, stream>>>(
      Pb, Sn, (long)256 * Sn, lnSt, Sn, (long)Dn * Sn,
      A16, Dn, (long)256 * Dn, nulb, nulf, nulf,
      nulf, nulf, 0, nulf, nulf, Sn, 0, 0,
      nullptr, nullptr, nullptr, nulf, nulf, nullptr, 0);
  k_headout<<<dim3(Hn, Bn), blk, 0, stream>>>(A16, sp_in_w, 3072, 2048, sp_in_b + 2048, obuf);
  k_gemm_mfma<<<dim3(8, 2, 1), blk, 0, stream>>>(
      obuf, Dn, 0, wspo, Dn, 0, hs, Dn, 0, nulb, sp_out_b, hs,
      nulf, nulf, 0, nulf, nulf, Dn, 0, 1,
      nullptr, nullptr, nullptr, nulf, nulf, nullptr, 0);

  // ---- FFN ----
  k_ln<<<256, blk, 0, stream>>>(hs, xn, g5, b5);
  k_gemm_mfma<<<dim3(32, 2, 1), blk, 0, stream>>>(
      xn, Dn, 0, wf1, Dn, 0, (float*)ubuf /*unused f32*/, 4096, 0, ubuf, fb1, nulf,
      nulf, nulf, 0, nulf, nulf, Dn, 0, 2,
      nullptr, nullptr, nullptr, nulf, nulf, nullptr, 0);
  k_gemm_mfma<<<dim3(8, 2, 1), blk, 0, stream>>>(
      ubuf, 4096, 0, wf2, 4096, 0, hs, Dn, 0, nulb, fb2, hs,
      nulf, nulf, 0, nulf, nulf, 4096, 0, 1,
      nullptr, nullptr, nullptr, nulf, nulf, nullptr, 0);
}

// Round 4
// 1280.617 us; speedup vs baseline: 1.6842x; 1.0956x over previous
//
#include <hip/hip_runtime.h>
#include <float.h>
#include <math.h>

// PoseHeadBlock, Round 4: R3 + dedicated 64x64-tile skinny MFMA GEMM for all
// z=1 GEMMs (they were latency-bound at 16-64 blocks of 128x128: 149us each,
// 0.7% occupancy). Big 128x128 kernel kept for z=16 scores/ctx GEMMs.

#define Bn 16
#define Jn 16
#define Ln 2048
#define Sn 256
#define Dn 1024
#define Hn 16
#define HDn 64

static const float EPSf = 1e-5f;
static const float SCALEf = 0.125f; // 1/sqrt(64)

typedef float4 f4;
typedef unsigned short u16;
typedef __attribute__((ext_vector_type(8))) short short8;
typedef __attribute__((ext_vector_type(4))) unsigned short us4;
typedef __attribute__((ext_vector_type(4))) float f32x4;

__device__ __forceinline__ u16 f2bf(float f) {
  unsigned u = __float_as_uint(f);
  unsigned r = (u + 0x7FFFu + ((u >> 16) & 1u)) >> 16;
  return (u16)r;
}

__device__ __forceinline__ float wave_sum(float v) {
#pragma unroll
  for (int o = 32; o; o >>= 1) v += __shfl_xor(v, o);
  return v;
}
__device__ __forceinline__ float wave_max(float v) {
#pragma unroll
  for (int o = 32; o; o >>= 1) v = fmaxf(v, __shfl_xor(v, o));
  return v;
}
__device__ __forceinline__ void block_reduce2(float& a, float& b) {
  __shared__ float la[4], lb[4];
  a = wave_sum(a); b = wave_sum(b);
  int t = threadIdx.x, w = t >> 6;
  __syncthreads();
  if ((t & 63) == 0) { la[w] = a; lb[w] = b; }
  __syncthreads();
  a = la[0] + la[1] + la[2] + la[3];
  b = lb[0] + lb[1] + lb[2] + lb[3];
}
__device__ __forceinline__ float block_max_bcast(float v) {
  __shared__ float lm[4];
  v = wave_max(v);
  int t = threadIdx.x;
  __syncthreads();
  if ((t & 63) == 0) lm[t >> 6] = v;
  __syncthreads();
  return fmaxf(fmaxf(lm[0], lm[1]), fmaxf(lm[2], lm[3]));
}
__device__ __forceinline__ float block_sum_bcast(float v) {
  __shared__ float ls[4];
  v = wave_sum(v);
  int t = threadIdx.x;
  __syncthreads();
  if ((t & 63) == 0) ls[t >> 6] = v;
  __syncthreads();
  return ls[0] + ls[1] + ls[2] + ls[3];
}

// ---- mask dtype probe: flag=1 -> int32 bools, 0 -> uint8 bools ----
__global__ __launch_bounds__(256) void k_probe(const int* __restrict__ tm, int* flag) {
  __shared__ int bad;
  int t = threadIdx.x;
  if (t == 0) bad = 0;
  __syncthreads();
  int loc = 0;
  for (int i = t; i < 4096; i += 256) {
    unsigned v = (unsigned)tm[i];
    if (v > 1u) loc = 1;
  }
  if (loc) bad = 1;
  __syncthreads();
  if (t == 0) *flag = bad ? 0 : 1;
}

// ---- per-row mean/rstd over D=1024 ----
__global__ __launch_bounds__(256) void k_rowstats(const float* __restrict__ x,
                                                  float* __restrict__ mean,
                                                  float* __restrict__ rstd) {
  int row = blockIdx.x, t = threadIdx.x;
  f4 v = *(const f4*)(x + (size_t)row * Dn + t * 4);
  float s = v.x + v.y + v.z + v.w;
  float s2 = v.x * v.x + v.y * v.y + v.z * v.z + v.w * v.w;
  block_reduce2(s, s2);
  if (t == 0) {
    float m = s * (1.f / Dn);
    float var = s2 * (1.f / Dn) - m * m;
    if (var < 0.f) var = 0.f;
    mean[row] = m;
    rstd[row] = rsqrtf(var + EPSf);
  }
}

// ---- LN + transpose: out[b][d][l] bf16 = LN(kv[b][l][d]) ----
__global__ __launch_bounds__(256) void k_lnt(const float* __restrict__ kv,
                                             const float* __restrict__ mean,
                                             const float* __restrict__ rstd,
                                             const float* __restrict__ g,
                                             const float* __restrict__ be,
                                             u16* __restrict__ out, int Lkv) {
  int b = blockIdx.z, d0 = blockIdx.x * 32, l0 = blockIdx.y * 32;
  __shared__ float tile[32][33];
  int t = threadIdx.x;
  int r = t >> 3, c4 = (t & 7) * 4;
  const float* kvb = kv + (size_t)b * Lkv * Dn;
  f4 v = *(const f4*)(kvb + (size_t)(l0 + r) * Dn + d0 + c4);
  float m = mean[(size_t)b * Lkv + l0 + r], rs = rstd[(size_t)b * Lkv + l0 + r];
  tile[r][c4 + 0] = (v.x - m) * rs * g[d0 + c4 + 0] + be[d0 + c4 + 0];
  tile[r][c4 + 1] = (v.y - m) * rs * g[d0 + c4 + 1] + be[d0 + c4 + 1];
  tile[r][c4 + 2] = (v.z - m) * rs * g[d0 + c4 + 2] + be[d0 + c4 + 2];
  tile[r][c4 + 3] = (v.w - m) * rs * g[d0 + c4 + 3] + be[d0 + c4 + 3];
  __syncthreads();
  int dr = t >> 3, l4 = (t & 7) * 4;
  us4 o;
  o.x = f2bf(tile[l4 + 0][dr]);
  o.y = f2bf(tile[l4 + 1][dr]);
  o.z = f2bf(tile[l4 + 2][dr]);
  o.w = f2bf(tile[l4 + 3][dr]);
  *(us4*)(out + (size_t)b * Dn * Lkv + (size_t)(d0 + dr) * Lkv + l0 + l4) = o;
}

// ---- weight f32 [K x ldw] (cols nofs..nofs+Nt) -> bf16 Bt[Nt][K] ----
__global__ __launch_bounds__(256) void k_wt(const float* __restrict__ W, int ldw,
                                            int nofs, int K, u16* __restrict__ out) {
  int n0 = blockIdx.x * 32, k0 = blockIdx.y * 32;
  __shared__ float tile[32][33];
  int t = threadIdx.x;
  int r = t >> 3, c4 = (t & 7) * 4; // r = k-row, c = n-col
  f4 v = *(const f4*)(W + (size_t)(k0 + r) * ldw + nofs + n0 + c4);
  tile[r][c4 + 0] = v.x; tile[r][c4 + 1] = v.y;
  tile[r][c4 + 2] = v.z; tile[r][c4 + 3] = v.w;
  __syncthreads();
  int nr = t >> 3, k4 = (t & 7) * 4;
  us4 o;
  o.x = f2bf(tile[k4 + 0][nr]);
  o.y = f2bf(tile[k4 + 1][nr]);
  o.z = f2bf(tile[k4 + 2][nr]);
  o.w = f2bf(tile[k4 + 3][nr]);
  *(us4*)(out + (size_t)(n0 + nr) * K + k0 + k4) = o;
}

// ---- film = cond @ film_w + film_b ; [B,2048] f32 ----
__global__ __launch_bounds__(256) void k_film(const float* __restrict__ cond,
                                              const float* __restrict__ fw,
                                              const float* __restrict__ fb,
                                              float* __restrict__ film) {
  int b = blockIdx.y, t = threadIdx.x;
  int n = blockIdx.x * 256 + t;
  __shared__ float cs[512];
  cs[t] = cond[b * 512 + t];
  cs[t + 256] = cond[b * 512 + 256 + t];
  __syncthreads();
  float acc = fb[n];
  for (int k = 0; k < 512; k++) acc = fmaf(cs[k], fw[(size_t)k * 2048 + n], acc);
  film[b * 2048 + n] = acc;
}

// ---- h' = h*(1+s)+sh -> hs f32 ; xn = LN(h') bf16 ----
__global__ __launch_bounds__(256) void k_film_apply_ln(
    const float* __restrict__ h, const float* __restrict__ film,
    const float* __restrict__ g, const float* __restrict__ be,
    float* __restrict__ hs, u16* __restrict__ xn) {
  int row = blockIdx.x, t = threadIdx.x, b = row >> 4;
  int c = t * 4;
  f4 hv = *(const f4*)(h + (size_t)row * Dn + c);
  f4 sv = *(const f4*)(film + (size_t)b * 2048 + c);
  f4 shv = *(const f4*)(film + (size_t)b * 2048 + 1024 + c);
  f4 v;
  v.x = hv.x * (1.f + sv.x) + shv.x;
  v.y = hv.y * (1.f + sv.y) + shv.y;
  v.z = hv.z * (1.f + sv.z) + shv.z;
  v.w = hv.w * (1.f + sv.w) + shv.w;
  *(f4*)(hs + (size_t)row * Dn + c) = v;
  float s = v.x + v.y + v.z + v.w;
  float s2 = v.x * v.x + v.y * v.y + v.z * v.z + v.w * v.w;
  block_reduce2(s, s2);
  float m = s * (1.f / Dn);
  float var = fmaxf(s2 * (1.f / Dn) - m * m, 0.f);
  float rs = rsqrtf(var + EPSf);
  us4 o;
  o.x = f2bf((v.x - m) * rs * g[c + 0] + be[c + 0]);
  o.y = f2bf((v.y - m) * rs * g[c + 1] + be[c + 1]);
  o.z = f2bf((v.z - m) * rs * g[c + 2] + be[c + 2]);
  o.w = f2bf((v.w - m) * rs * g[c + 3] + be[c + 3]);
  *(us4*)(xn + (size_t)row * Dn + c) = o;
}

// ---- row LN f32 -> bf16 ----
__global__ __launch_bounds__(256) void k_ln(const float* __restrict__ x,
                                            u16* __restrict__ y,
                                            const float* __restrict__ g,
                                            const float* __restrict__ be) {
  int row = blockIdx.x, t = threadIdx.x;
  int c = t * 4;
  f4 v = *(const f4*)(x + (size_t)row * Dn + c);
  float s = v.x + v.y + v.z + v.w;
  float s2 = v.x * v.x + v.y * v.y + v.z * v.z + v.w * v.w;
  block_reduce2(s, s2);
  float m = s * (1.f / Dn);
  float var = fmaxf(s2 * (1.f / Dn) - m * m, 0.f);
  float rs = rsqrtf(var + EPSf);
  us4 o;
  o.x = f2bf((v.x - m) * rs * g[c + 0] + be[c + 0]);
  o.y = f2bf((v.y - m) * rs * g[c + 1] + be[c + 1]);
  o.z = f2bf((v.z - m) * rs * g[c + 2] + be[c + 2]);
  o.w = f2bf((v.w - m) * rs * g[c + 3] + be[c + 3]);
  *(us4*)(y + (size_t)row * Dn + c) = o;
}

#define LSTR 72

// ============ big MFMA GEMM: C[M][N] = A(bf16)[M][K] @ Bt[N][K]^T, 128x128 ============
// bmode: 0 = Bt bf16; 1 = B from f32 KV rows with fused LN.
// epi: 0 f32 out (+bias); 3 f32 token-scores (scale+bias+mask); 4 f32 *SCALE.
__global__ __launch_bounds__(256) void k_gemm_mfma(
    const u16* __restrict__ A, int lda, long sA,
    const void* __restrict__ Bsrc, int ldb, long sB,
    float* __restrict__ C, int ldc, long sC,
    const float* __restrict__ nmean, const float* __restrict__ nrstd, int sStat,
    const float* __restrict__ ngamma, const float* __restrict__ nbeta,
    int K, int bmode, int epi,
    const void* tokmask, const void* palign, const int* __restrict__ slots,
    const float* __restrict__ pbias, const float* __restrict__ sbias,
    const int* __restrict__ flagp, int Nkv) {
  int bz = blockIdx.z;
  A += (size_t)bz * sA;
  const u16* Bt = (const u16*)Bsrc + (bmode == 0 ? (size_t)bz * sB : 0);
  const float* KV = (const float*)Bsrc + (bmode == 1 ? (size_t)bz * sB : 0);
  C += (size_t)bz * sC;
  const float* mn = nmean ? nmean + (size_t)bz * sStat : nullptr;
  const float* rsd = nrstd ? nrstd + (size_t)bz * sStat : nullptr;

  __shared__ u16 As[128 * LSTR];
  __shared__ u16 Bs[128 * LSTR];
  int t = threadIdx.x;
  int m0 = blockIdx.y * 128, n0 = blockIdx.x * 128;
  int w = t >> 6, l = t & 63;
  int wr = (w >> 1) * 64, wc = (w & 1) * 64;
  int lr = l & 15, lg = l >> 4;

  f32x4 acc[4][4];
#pragma unroll
  for (int m = 0; m < 4; m++)
#pragma unroll
    for (int n = 0; n < 4; n++) acc[m][n] = (f32x4){0.f, 0.f, 0.f, 0.f};

  for (int k0 = 0; k0 < K; k0 += 64) {
#pragma unroll
    for (int i = 0; i < 4; i++) {
      int idx = i * 256 + t;
      int r = idx >> 3, c = (idx & 7) * 8;
      *(short8*)&As[r * LSTR + c] =
          *(const short8*)(const void*)(A + (size_t)(m0 + r) * lda + k0 + c);
    }
    if (bmode == 0) {
#pragma unroll
      for (int i = 0; i < 4; i++) {
        int idx = i * 256 + t;
        int r = idx >> 3, c = (idx & 7) * 8;
        *(short8*)&Bs[r * LSTR + c] =
            *(const short8*)(const void*)(Bt + (size_t)(n0 + r) * ldb + k0 + c);
      }
    } else {
#pragma unroll
      for (int i = 0; i < 8; i++) {
        int idx = i * 256 + t;
        int r = idx >> 4, c = (idx & 15) * 4;
        f4 v = *(const f4*)(KV + (size_t)(n0 + r) * ldb + k0 + c);
        float m = mn[n0 + r], rs = rsd[n0 + r];
        us4 o;
        o.x = f2bf((v.x - m) * rs * ngamma[k0 + c + 0] + nbeta[k0 + c + 0]);
        o.y = f2bf((v.y - m) * rs * ngamma[k0 + c + 1] + nbeta[k0 + c + 1]);
        o.z = f2bf((v.z - m) * rs * ngamma[k0 + c + 2] + nbeta[k0 + c + 2]);
        o.w = f2bf((v.w - m) * rs * ngamma[k0 + c + 3] + nbeta[k0 + c + 3]);
        *(us4*)&Bs[r * LSTR + c] = o;
      }
    }
    __syncthreads();
#pragma unroll
    for (int ks = 0; ks < 2; ks++) {
      short8 a[4], b[4];
#pragma unroll
      for (int m = 0; m < 4; m++)
        a[m] = *(const short8*)&As[(wr + m * 16 + lr) * LSTR + ks * 32 + lg * 8];
#pragma unroll
      for (int n = 0; n < 4; n++)
        b[n] = *(const short8*)&Bs[(wc + n * 16 + lr) * LSTR + ks * 32 + lg * 8];
#pragma unroll
      for (int m = 0; m < 4; m++)
#pragma unroll
        for (int n = 0; n < 4; n++)
          acc[m][n] = __builtin_amdgcn_mfma_f32_16x16x32_bf16(a[m], b[n], acc[m][n], 0, 0, 0);
    }
    __syncthreads();
  }

  int m32 = (epi == 3) ? *flagp : 0;
#pragma unroll
  for (int m = 0; m < 4; m++) {
#pragma unroll
    for (int n = 0; n < 4; n++) {
#pragma unroll
      for (int i = 0; i < 4; i++) {
        int gr = m0 + wr + m * 16 + lg * 4 + i;
        int gc = n0 + wc + n * 16 + lr;
        float v = acc[m][n][i];
        if (epi == 3) {
          v *= SCALEf;
          int hh = gr >> 4, qq = gr & 15;
          size_t pidx = (size_t)(bz * Jn + qq) * Nkv + gc;
          bool pm = m32 ? (((const int*)palign)[pidx] != 0)
                        : (((const unsigned char*)palign)[pidx] != 0);
          if (pm) v += pbias[hh];
          int sl = slots[(size_t)bz * Nkv + gc];
          sl = sl < 0 ? 0 : (sl > 3 ? 3 : sl);
          v += sbias[hh * 4 + sl];
          bool tm = m32 ? (((const int*)tokmask)[(size_t)bz * Nkv + gc] != 0)
                        : (((const unsigned char*)tokmask)[(size_t)bz * Nkv + gc] != 0);
          if (!tm) v = -FLT_MAX;
        } else if (epi == 4) {
          v *= SCALEf;
        }
        C[(size_t)gr * ldc + gc] = v;
      }
    }
  }
}

// ============ skinny MFMA GEMM: 64x64 tile, 4 waves (1 strip each) ============
// For M=256 GEMMs: grid (N/64, 4, z). epi: 0 f32+bias; 1 f32+bias+resid;
// 2 bf16+bias+gelu.
__global__ __launch_bounds__(256) void k_gemm_sk(
    const u16* __restrict__ A, int lda, long sA,
    const u16* __restrict__ Bt, int ldb, long sB,
    float* __restrict__ C, int ldc, long sC,
    u16* __restrict__ Cb,
    const float* __restrict__ bias, const float* __restrict__ resid,
    int K, int epi) {
  int bz = blockIdx.z;
  A += (size_t)bz * sA;
  Bt += (size_t)bz * sB;
  if (C) C += (size_t)bz * sC;
  if (Cb) Cb += (size_t)bz * sC;
  if (resid) resid += (size_t)bz * sC;
  __shared__ u16 As[64 * LSTR];
  __shared__ u16 Bs[64 * LSTR];
  int t = threadIdx.x;
  int m0 = blockIdx.y * 64, n0 = blockIdx.x * 64;
  int w = t >> 6, l = t & 63;
  int wr = w * 16;
  int lr = l & 15, lg = l >> 4;
  f32x4 acc[4];
#pragma unroll
  for (int n = 0; n < 4; n++) acc[n] = (f32x4){0.f, 0.f, 0.f, 0.f};
  for (int k0 = 0; k0 < K; k0 += 64) {
#pragma unroll
    for (int i = 0; i < 2; i++) {
      int idx = i * 256 + t;
      int r = idx >> 3, c = (idx & 7) * 8;
      *(short8*)&As[r * LSTR + c] =
          *(const short8*)(const void*)(A + (size_t)(m0 + r) * lda + k0 + c);
      *(short8*)&Bs[r * LSTR + c] =
          *(const short8*)(const void*)(Bt + (size_t)(n0 + r) * ldb + k0 + c);
    }
    __syncthreads();
#pragma unroll
    for (int ks = 0; ks < 2; ks++) {
      short8 a = *(const short8*)&As[(wr + lr) * LSTR + ks * 32 + lg * 8];
#pragma unroll
      for (int n = 0; n < 4; n++) {
        short8 b = *(const short8*)&Bs[(n * 16 + lr) * LSTR + ks * 32 + lg * 8];
        acc[n] = __builtin_amdgcn_mfma_f32_16x16x32_bf16(a, b, acc[n], 0, 0, 0);
      }
    }
    __syncthreads();
  }
#pragma unroll
  for (int n = 0; n < 4; n++) {
#pragma unroll
    for (int i = 0; i < 4; i++) {
      int gr = m0 + wr + lg * 4 + i;
      int gc = n0 + n * 16 + lr;
      float v = acc[n][i];
      if (bias) v += bias[gc];
      if (epi == 1) v += resid[(size_t)gr * ldc + gc];
      if (epi == 2) {
        v = 0.5f * v * (1.f + erff(v * 0.70710678118654752f));
        Cb[(size_t)gr * ldc + gc] = f2bf(v);
      } else {
        C[(size_t)gr * ldc + gc] = v;
      }
    }
  }
}

// ---- row softmax f32 in -> bf16 out; ncols in {256, 2048} ----
__global__ __launch_bounds__(256) void k_softmax(const float* __restrict__ x,
                                                 u16* __restrict__ p, int ncols) {
  int row = blockIdx.x, t = threadIdx.x;
  const float* xr = x + (size_t)row * ncols;
  u16* pr = p + (size_t)row * ncols;
  int cnt = ncols >> 8;
  float r[8];
  float mx = -FLT_MAX;
  for (int i = 0; i < cnt; i++) {
    r[i] = xr[t + (i << 8)];
    mx = fmaxf(mx, r[i]);
  }
  mx = block_max_bcast(mx);
  float sm = 0.f;
  for (int i = 0; i < cnt; i++) {
    r[i] = expf(r[i] - mx);
    sm += r[i];
  }
  sm = block_sum_bcast(sm);
  float inv = 1.f / sm;
  for (int i = 0; i < cnt; i++) pr[t + (i << 8)] = f2bf(r[i] * inv);
}

// ---- self-attention over J=16 per (b,h); qkv f32 [256][3072]; out bf16 ----
__global__ __launch_bounds__(256) void k_sa(const float* __restrict__ qkv,
                                            u16* __restrict__ o) {
  int h = blockIdx.x, b = blockIdx.y, t = threadIdx.x;
  __shared__ float qs[16][68], ks[16][68], vs[16][68], ps[16][16];
  int rr = t >> 4, d4 = (t & 15) * 4;
  size_t base = (size_t)(b * Jn + rr) * 3072 + h * HDn + d4;
  *(f4*)&qs[rr][d4] = *(const f4*)(qkv + base);
  *(f4*)&ks[rr][d4] = *(const f4*)(qkv + base + 1024);
  *(f4*)&vs[rr][d4] = *(const f4*)(qkv + base + 2048);
  __syncthreads();
  int j1 = t >> 4, j2 = t & 15;
  float s = 0.f;
  for (int d = 0; d < 64; d++) s = fmaf(qs[j1][d], ks[j2][d], s);
  s *= SCALEf;
  float m = s;
#pragma unroll
  for (int oo = 8; oo; oo >>= 1) m = fmaxf(m, __shfl_xor(m, oo));
  float e = expf(s - m);
  float sm = e;
#pragma unroll
  for (int oo = 8; oo; oo >>= 1) sm += __shfl_xor(sm, oo);
  ps[j1][j2] = e / sm;
  __syncthreads();
  f4 acc = make_float4(0.f, 0.f, 0.f, 0.f);
#pragma unroll
  for (int k = 0; k < 16; k++) {
    float p = ps[j1][k];
    f4 v = *(const f4*)&vs[k][d4];
    acc.x += p * v.x; acc.y += p * v.y; acc.z += p * v.z; acc.w += p * v.w;
  }
  us4 ov;
  ov.x = f2bf(acc.x); ov.y = f2bf(acc.y); ov.z = f2bf(acc.z); ov.w = f2bf(acc.w);
  *(us4*)(o + (size_t)(b * Jn + j1) * Dn + h * HDn + d4) = ov;
}

// ---- qw[b, h*16+j, c] = sum_d q[(b,j), h*64+d] * W[c*ldw + wofs + h*64 + d]; bf16 out ----
__global__ __launch_bounds__(256) void k_qw(const float* __restrict__ q,
                                            const float* __restrict__ W,
                                            int ldw, int wofs, u16* __restrict__ qw) {
  int b = blockIdx.z, h = blockIdx.y, c0 = blockIdx.x * 256;
  int t = threadIdx.x;
  __shared__ float qs[16][68];
  int rr = t >> 4, d4 = (t & 15) * 4;
  *(f4*)&qs[rr][d4] = *(const f4*)(q + (size_t)(b * Jn + rr) * Dn + h * HDn + d4);
  __syncthreads();
  int c = c0 + t;
  float acc[16] = {};
  const float* wr = W + (size_t)c * ldw + wofs + h * HDn;
  for (int d = 0; d < 64; d += 4) {
    f4 wv = *(const f4*)(wr + d);
#pragma unroll
    for (int j = 0; j < 16; j++) {
      acc[j] += wv.x * qs[j][d] + wv.y * qs[j][d + 1] + wv.z * qs[j][d + 2] + wv.w * qs[j][d + 3];
    }
  }
#pragma unroll
  for (int j = 0; j < 16; j++)
    qw[(size_t)(b * 256 + h * Jn + j) * Dn + c] = f2bf(acc[j]);
}

// ---- o[(b,j), h*64+d] = bias + sum_c ctx[b,h*16+j,c]*W[c*ldw+wofs+h*64+d]; bf16 out ----
__global__ __launch_bounds__(256) void k_headout(
    const float* __restrict__ ctx, const float* __restrict__ W,
    int ldw, int wofs, const float* __restrict__ bias, u16* __restrict__ o) {
  int h = blockIdx.x, b = blockIdx.y, t = threadIdx.x;
  __shared__ float cs[16][132];
  int j = t >> 4, d4 = (t & 15) * 4;
  f4 acc = make_float4(0.f, 0.f, 0.f, 0.f);
  for (int cc = 0; cc < 1024; cc += 128) {
    __syncthreads();
#pragma unroll
    for (int i = 0; i < 2; i++) {
      int f = t + i * 256;
      int row = f >> 5, c4 = (f & 31) * 4;
      *(f4*)&cs[row][c4] = *(const f4*)(ctx + (size_t)(b * 256 + h * Jn + row) * Dn + cc + c4);
    }
    __syncthreads();
    for (int c = 0; c < 128; c++) {
      f4 wv = *(const f4*)(W + (size_t)(cc + c) * ldw + wofs + h * HDn + d4);
      float a = cs[j][c];
      acc.x += a * wv.x; acc.y += a * wv.y; acc.z += a * wv.z; acc.w += a * wv.w;
    }
  }
  f4 bv = *(const f4*)(bias + h * HDn + d4);
  us4 ov;
  ov.x = f2bf(acc.x + bv.x); ov.y = f2bf(acc.y + bv.y);
  ov.z = f2bf(acc.z + bv.z); ov.w = f2bf(acc.w + bv.w);
  *(us4*)(o + (size_t)(b * Jn + j) * Dn + h * HDn + d4) = ov;
}

extern "C" void kernel_launch(void* const* d_in, const int* in_sizes, int n_in,
                              void* d_out, int out_size, void* d_ws, size_t ws_size,
                              hipStream_t stream) {
  (void)in_sizes; (void)n_in; (void)out_size; (void)ws_size;
  const float* h       = (const float*)d_in[0];
  const float* cond    = (const float*)d_in[1];
  const float* tkv     = (const float*)d_in[2];
  const void*  tmask   = d_in[3];
  const void*  palign  = d_in[4];
  const int*   slots   = (const int*)d_in[5];
  const float* skv     = (const float*)d_in[6];
  const float* film_w  = (const float*)d_in[7];
  const float* film_b  = (const float*)d_in[8];
  const float* ln_g    = (const float*)d_in[9];
  const float* ln_b    = (const float*)d_in[10];
  const float* sa_in_w = (const float*)d_in[11];
  const float* sa_in_b = (const float*)d_in[12];
  const float* sa_out_w= (const float*)d_in[13];
  const float* sa_out_b= (const float*)d_in[14];
  const float* cq_w    = (const float*)d_in[15];
  const float* cq_b    = (const float*)d_in[16];
  const float* ck_w    = (const float*)d_in[17];
  const float* cv_w    = (const float*)d_in[19];
  const float* cv_b    = (const float*)d_in[20];
  const float* co_w    = (const float*)d_in[21];
  const float* co_b    = (const float*)d_in[22];
  const float* sp_in_w = (const float*)d_in[23];
  const float* sp_in_b = (const float*)d_in[24];
  const float* sp_out_w= (const float*)d_in[25];
  const float* sp_out_b= (const float*)d_in[26];
  const float* pbias   = (const float*)d_in[27];
  const float* sbias   = (const float*)d_in[28];
  const float* fw1     = (const float*)d_in[29];
  const float* fb1     = (const float*)d_in[30];
  const float* fw2     = (const float*)d_in[31];
  const float* fb2     = (const float*)d_in[32];

  char* wsp = (char*)d_ws;
  size_t off = 0;
  auto carve = [&](size_t bytes) -> char* {
    char* p = wsp + off;
    off = (off + bytes + 255) & ~(size_t)255;
    return p;
  };
  int*   flag  = (int*)carve(256);
  float* stTm  = (float*)carve((size_t)Bn * Ln * 4);
  float* stTr  = (float*)carve((size_t)Bn * Ln * 4);
  float* stSm  = (float*)carve((size_t)Bn * Sn * 4);
  float* stSr  = (float*)carve((size_t)Bn * Sn * 4);
  float* film  = (float*)carve((size_t)Bn * 2048 * 4);
  u16*   xn    = (u16*)carve((size_t)256 * Dn * 2);
  float* qbuf  = (float*)carve((size_t)256 * Dn * 4);
  u16*   obuf  = (u16*)carve((size_t)256 * Dn * 2);
  u16*   qw    = (u16*)carve((size_t)Bn * 256 * Dn * 2);
  u16*   Pb    = (u16*)carve((size_t)Bn * 256 * Ln * 2);
  float* big   = (float*)carve((size_t)Bn * 256 * Ln * 4);  // scores / qkv / A16 / ubuf
  u16*   lnTt  = (u16*)carve((size_t)Bn * Dn * Ln * 2);
  u16*   lnSt  = (u16*)carve((size_t)Bn * Dn * Sn * 2);
  u16*   wsa   = (u16*)carve((size_t)3072 * Dn * 2);
  u16*   wso   = (u16*)carve((size_t)Dn * Dn * 2);
  u16*   wcq   = (u16*)carve((size_t)Dn * Dn * 2);
  u16*   wco   = (u16*)carve((size_t)Dn * Dn * 2);
  u16*   wspq  = (u16*)carve((size_t)Dn * Dn * 2);
  u16*   wspo  = (u16*)carve((size_t)Dn * Dn * 2);
  u16*   wf1   = (u16*)carve((size_t)4096 * Dn * 2);
  u16*   wf2   = (u16*)carve((size_t)Dn * 4096 * 2);

  float* qkv  = big;          // f32 [256][3072], SA only
  float* scores = big;        // f32 [B][256][L]
  float* A16  = big;          // f32 [B][256][1024] ctx out
  u16*   ubuf = (u16*)big;    // bf16 [256][4096], FFN only
  float* hs = (float*)d_out;

  const float* g0 = ln_g + 0 * Dn; const float* b0 = ln_b + 0 * Dn;
  const float* g1 = ln_g + 1 * Dn; const float* b1 = ln_b + 1 * Dn;
  const float* g2 = ln_g + 2 * Dn; const float* b2 = ln_b + 2 * Dn;
  const float* g3 = ln_g + 3 * Dn; const float* b3 = ln_b + 3 * Dn;
  const float* g4 = ln_g + 4 * Dn; const float* b4 = ln_b + 4 * Dn;
  const float* g5 = ln_g + 5 * Dn; const float* b5 = ln_b + 5 * Dn;

  dim3 blk(256);
  const float* nulf = nullptr;
  u16* nulb = nullptr;

  // ---- prep ----
  k_probe<<<1, blk, 0, stream>>>((const int*)tmask, flag);
  k_rowstats<<<Bn * Ln, blk, 0, stream>>>(tkv, stTm, stTr);
  k_rowstats<<<Bn * Sn, blk, 0, stream>>>(skv, stSm, stSr);
  k_lnt<<<dim3(32, 64, Bn), blk, 0, stream>>>(tkv, stTm, stTr, g2, b2, lnTt, Ln);
  k_lnt<<<dim3(32, 8, Bn), blk, 0, stream>>>(skv, stSm, stSr, g4, b4, lnSt, Sn);
  k_wt<<<dim3(96, 32), blk, 0, stream>>>(sa_in_w, 3072, 0, Dn, wsa);
  k_wt<<<dim3(32, 32), blk, 0, stream>>>(sa_out_w, 1024, 0, Dn, wso);
  k_wt<<<dim3(32, 32), blk, 0, stream>>>(cq_w, 1024, 0, Dn, wcq);
  k_wt<<<dim3(32, 32), blk, 0, stream>>>(co_w, 1024, 0, Dn, wco);
  k_wt<<<dim3(32, 32), blk, 0, stream>>>(sp_in_w, 3072, 0, Dn, wspq);
  k_wt<<<dim3(32, 32), blk, 0, stream>>>(sp_out_w, 1024, 0, Dn, wspo);
  k_wt<<<dim3(128, 32), blk, 0, stream>>>(fw1, 4096, 0, Dn, wf1);
  k_wt<<<dim3(32, 128), blk, 0, stream>>>(fw2, 1024, 0, 4096, wf2);
  k_film<<<dim3(8, Bn), blk, 0, stream>>>(cond, film_w, film_b, film);
  k_film_apply_ln<<<256, blk, 0, stream>>>(h, film, g0, b0, hs, xn);

  // ---- self-attention ----
  k_gemm_sk<<<dim3(48, 4, 1), blk, 0, stream>>>(
      xn, Dn, 0, wsa, Dn, 0, qkv, 3072, 0, nulb, sa_in_b, nulf, Dn, 0);
  k_sa<<<dim3(Hn, Bn), blk, 0, stream>>>(qkv, obuf);
  k_gemm_sk<<<dim3(16, 4, 1), blk, 0, stream>>>(
      obuf, Dn, 0, wso, Dn, 0, hs, Dn, 0, nulb, sa_out_b, hs, Dn, 1);

  // ---- masked token cross-attention (transpose trick) ----
  k_ln<<<256, blk, 0, stream>>>(hs, xn, g1, b1);
  k_gemm_sk<<<dim3(16, 4, 1), blk, 0, stream>>>(
      xn, Dn, 0, wcq, Dn, 0, qbuf, Dn, 0, nulb, cq_b, nulf, Dn, 0);
  k_qw<<<dim3(4, Hn, Bn), blk, 0, stream>>>(qbuf, ck_w, Dn, 0, qw);
  k_gemm_mfma<<<dim3(16, 2, Bn), blk, 0, stream>>>(
      qw, Dn, (long)256 * Dn, tkv, Dn, (long)Ln * Dn,
      scores, Ln, (long)256 * Ln,
      stTm, stTr, Ln, g2, b2, Dn, 1, 3,
      tmask, palign, slots, pbias, sbias, flag, Ln);
  k_softmax<<<Bn * 256, blk, 0, stream>>>(scores, Pb, Ln);
  k_gemm_mfma<<<dim3(8, 2, Bn), blk, 0, stream>>>(
      Pb, Ln, (long)256 * Ln, lnTt, Ln, (long)Dn * Ln,
      A16, Dn, (long)256 * Dn,
      nulf, nulf, 0, nulf, nulf, Ln, 0, 0,
      nullptr, nullptr, nullptr, nulf, nulf, nullptr, 0);
  k_headout<<<dim3(Hn, Bn), blk, 0, stream>>>(A16, cv_w, Dn, 0, cv_b, obuf);
  k_gemm_sk<<<dim3(16, 4, 1), blk, 0, stream>>>(
      obuf, Dn, 0, wco, Dn, 0, hs, Dn, 0, nulb, co_b, hs, Dn, 1);

  // ---- spatial cross-attention ----
  k_ln<<<256, blk, 0, stream>>>(hs, xn, g3, b3);
  k_gemm_sk<<<dim3(16, 4, 1), blk, 0, stream>>>(
      xn, Dn, 0, wspq, Dn, 0, qbuf, Dn, 0, nulb, sp_in_b, nulf, Dn, 0);
  k_qw<<<dim3(4, Hn, Bn), blk, 0, stream>>>(qbuf, sp_in_w, 3072, 1024, qw);
  k_gemm_mfma<<<dim3(2, 2, Bn), blk, 0, stream>>>(
      qw, Dn, (long)256 * Dn, skv, Dn, (long)Sn * Dn,
      scores, Sn, (long)256 * Sn,
      stSm, stSr, Sn, g4, b4, Dn, 1, 4,
      nullptr, nullptr, nullptr, nulf, nulf, nullptr, Sn);
  k_softmax<<<Bn * 256, blk, 0, stream>>>(scores, Pb, Sn);
  k_gemm_mfma<<<dim3(8, 2, Bn), blk, 0, stream>>>(
      Pb, Sn, (long)256 * Sn, lnSt, Sn, (long)Dn * Sn,
      A16, Dn, (long)256 * Dn,
      nulf, nulf, 0, nulf, nulf, Sn, 0, 0,
      nullptr, nullptr, nullptr, nulf, nulf, nullptr, 0);
  k_headout<<<dim3(Hn, Bn), blk, 0, stream>>>(A16, sp_in_w, 3072, 2048, sp_in_b + 2048, obuf);
  k_gemm_sk<<<dim3(16, 4, 1), blk, 0, stream>>>(
      obuf, Dn, 0, wspo, Dn, 0, hs, Dn, 0, nulb, sp_out_b, hs, Dn, 1);

  // ---- FFN ----
  k_ln<<<256, blk, 0, stream>>>(hs, xn, g5, b5);
  k_gemm_sk<<<dim3(64, 4, 1), blk, 0, stream>>>(
      xn, Dn, 0, wf1, Dn, 0, nullptr, 4096, 0, ubuf, fb1, nulf, Dn, 2);
  k_gemm_sk<<<dim3(16, 4, 1), blk, 0, stream>>>(
      ubuf, 4096, 0, wf2, 4096, 0, hs, Dn, 0, nulb, fb2, hs, 4096, 1);
}

// Round 5
// 981.855 us; speedup vs baseline: 2.1966x; 1.3043x over previous
//
#include <hip/hip_runtime.h>
#include <float.h>
#include <math.h>

// PoseHeadBlock, Round 5: R4 + (1) k_qw/k_headout replaced by per-head MFMA
// GEMMs (they were scalar latency-bound loops, 134us each), (2) FFN2 split-K
// x4 (was 64 blocks x 64 serial K-iters = 133us), (3) ctx/q intermediates in
// bf16 to feed the new head GEMMs.

#define Bn 16
#define Jn 16
#define Ln 2048
#define Sn 256
#define Dn 1024
#define Hn 16
#define HDn 64

static const float EPSf = 1e-5f;
static const float SCALEf = 0.125f; // 1/sqrt(64)

typedef float4 f4;
typedef unsigned short u16;
typedef __attribute__((ext_vector_type(8))) short short8;
typedef __attribute__((ext_vector_type(4))) unsigned short us4;
typedef __attribute__((ext_vector_type(4))) float f32x4;

__device__ __forceinline__ u16 f2bf(float f) {
  unsigned u = __float_as_uint(f);
  unsigned r = (u + 0x7FFFu + ((u >> 16) & 1u)) >> 16;
  return (u16)r;
}

__device__ __forceinline__ float wave_sum(float v) {
#pragma unroll
  for (int o = 32; o; o >>= 1) v += __shfl_xor(v, o);
  return v;
}
__device__ __forceinline__ float wave_max(float v) {
#pragma unroll
  for (int o = 32; o; o >>= 1) v = fmaxf(v, __shfl_xor(v, o));
  return v;
}
__device__ __forceinline__ void block_reduce2(float& a, float& b) {
  __shared__ float la[4], lb[4];
  a = wave_sum(a); b = wave_sum(b);
  int t = threadIdx.x, w = t >> 6;
  __syncthreads();
  if ((t & 63) == 0) { la[w] = a; lb[w] = b; }
  __syncthreads();
  a = la[0] + la[1] + la[2] + la[3];
  b = lb[0] + lb[1] + lb[2] + lb[3];
}
__device__ __forceinline__ float block_max_bcast(float v) {
  __shared__ float lm[4];
  v = wave_max(v);
  int t = threadIdx.x;
  __syncthreads();
  if ((t & 63) == 0) lm[t >> 6] = v;
  __syncthreads();
  return fmaxf(fmaxf(lm[0], lm[1]), fmaxf(lm[2], lm[3]));
}
__device__ __forceinline__ float block_sum_bcast(float v) {
  __shared__ float ls[4];
  v = wave_sum(v);
  int t = threadIdx.x;
  __syncthreads();
  if ((t & 63) == 0) ls[t >> 6] = v;
  __syncthreads();
  return ls[0] + ls[1] + ls[2] + ls[3];
}

// ---- mask dtype probe: flag=1 -> int32 bools, 0 -> uint8 bools ----
__global__ __launch_bounds__(256) void k_probe(const int* __restrict__ tm, int* flag) {
  __shared__ int bad;
  int t = threadIdx.x;
  if (t == 0) bad = 0;
  __syncthreads();
  int loc = 0;
  for (int i = t; i < 4096; i += 256) {
    unsigned v = (unsigned)tm[i];
    if (v > 1u) loc = 1;
  }
  if (loc) bad = 1;
  __syncthreads();
  if (t == 0) *flag = bad ? 0 : 1;
}

// ---- per-row mean/rstd over D=1024 ----
__global__ __launch_bounds__(256) void k_rowstats(const float* __restrict__ x,
                                                  float* __restrict__ mean,
                                                  float* __restrict__ rstd) {
  int row = blockIdx.x, t = threadIdx.x;
  f4 v = *(const f4*)(x + (size_t)row * Dn + t * 4);
  float s = v.x + v.y + v.z + v.w;
  float s2 = v.x * v.x + v.y * v.y + v.z * v.z + v.w * v.w;
  block_reduce2(s, s2);
  if (t == 0) {
    float m = s * (1.f / Dn);
    float var = s2 * (1.f / Dn) - m * m;
    if (var < 0.f) var = 0.f;
    mean[row] = m;
    rstd[row] = rsqrtf(var + EPSf);
  }
}

// ---- LN + transpose: out[b][d][l] bf16 = LN(kv[b][l][d]) ----
__global__ __launch_bounds__(256) void k_lnt(const float* __restrict__ kv,
                                             const float* __restrict__ mean,
                                             const float* __restrict__ rstd,
                                             const float* __restrict__ g,
                                             const float* __restrict__ be,
                                             u16* __restrict__ out, int Lkv) {
  int b = blockIdx.z, d0 = blockIdx.x * 32, l0 = blockIdx.y * 32;
  __shared__ float tile[32][33];
  int t = threadIdx.x;
  int r = t >> 3, c4 = (t & 7) * 4;
  const float* kvb = kv + (size_t)b * Lkv * Dn;
  f4 v = *(const f4*)(kvb + (size_t)(l0 + r) * Dn + d0 + c4);
  float m = mean[(size_t)b * Lkv + l0 + r], rs = rstd[(size_t)b * Lkv + l0 + r];
  tile[r][c4 + 0] = (v.x - m) * rs * g[d0 + c4 + 0] + be[d0 + c4 + 0];
  tile[r][c4 + 1] = (v.y - m) * rs * g[d0 + c4 + 1] + be[d0 + c4 + 1];
  tile[r][c4 + 2] = (v.z - m) * rs * g[d0 + c4 + 2] + be[d0 + c4 + 2];
  tile[r][c4 + 3] = (v.w - m) * rs * g[d0 + c4 + 3] + be[d0 + c4 + 3];
  __syncthreads();
  int dr = t >> 3, l4 = (t & 7) * 4;
  us4 o;
  o.x = f2bf(tile[l4 + 0][dr]);
  o.y = f2bf(tile[l4 + 1][dr]);
  o.z = f2bf(tile[l4 + 2][dr]);
  o.w = f2bf(tile[l4 + 3][dr]);
  *(us4*)(out + (size_t)b * Dn * Lkv + (size_t)(d0 + dr) * Lkv + l0 + l4) = o;
}

// ---- weight f32 [K x ldw] (cols nofs..nofs+Nt) -> bf16 Bt[Nt][K] (transpose) ----
__global__ __launch_bounds__(256) void k_wt(const float* __restrict__ W, int ldw,
                                            int nofs, int K, u16* __restrict__ out) {
  int n0 = blockIdx.x * 32, k0 = blockIdx.y * 32;
  __shared__ float tile[32][33];
  int t = threadIdx.x;
  int r = t >> 3, c4 = (t & 7) * 4; // r = k-row, c = n-col
  f4 v = *(const f4*)(W + (size_t)(k0 + r) * ldw + nofs + n0 + c4);
  tile[r][c4 + 0] = v.x; tile[r][c4 + 1] = v.y;
  tile[r][c4 + 2] = v.z; tile[r][c4 + 3] = v.w;
  __syncthreads();
  int nr = t >> 3, k4 = (t & 7) * 4;
  us4 o;
  o.x = f2bf(tile[k4 + 0][nr]);
  o.y = f2bf(tile[k4 + 1][nr]);
  o.z = f2bf(tile[k4 + 2][nr]);
  o.w = f2bf(tile[k4 + 3][nr]);
  *(us4*)(out + (size_t)(n0 + nr) * K + k0 + k4) = o;
}

// ---- straight slice copy f32 -> bf16: out[r][0..1023] = W[r*ldw + nofs + c] ----
__global__ __launch_bounds__(256) void k_cvt(const float* __restrict__ W, int ldw,
                                             int nofs, u16* __restrict__ out) {
  size_t idx = ((size_t)blockIdx.x * 256 + threadIdx.x) * 8;
  int r = (int)(idx >> 10), c = (int)(idx & 1023);
  const float* src = W + (size_t)r * ldw + nofs + c;
  f4 v0 = *(const f4*)src;
  f4 v1 = *(const f4*)(src + 4);
  us4 o0, o1;
  o0.x = f2bf(v0.x); o0.y = f2bf(v0.y); o0.z = f2bf(v0.z); o0.w = f2bf(v0.w);
  o1.x = f2bf(v1.x); o1.y = f2bf(v1.y); o1.z = f2bf(v1.z); o1.w = f2bf(v1.w);
  *(us4*)(out + idx) = o0;
  *(us4*)(out + idx + 4) = o1;
}

// ---- film = cond @ film_w + film_b ; [B,2048] f32 ----
__global__ __launch_bounds__(256) void k_film(const float* __restrict__ cond,
                                              const float* __restrict__ fw,
                                              const float* __restrict__ fb,
                                              float* __restrict__ film) {
  int b = blockIdx.y, t = threadIdx.x;
  int n = blockIdx.x * 256 + t;
  __shared__ float cs[512];
  cs[t] = cond[b * 512 + t];
  cs[t + 256] = cond[b * 512 + 256 + t];
  __syncthreads();
  float acc = fb[n];
  for (int k = 0; k < 512; k++) acc = fmaf(cs[k], fw[(size_t)k * 2048 + n], acc);
  film[b * 2048 + n] = acc;
}

// ---- h' = h*(1+s)+sh -> hs f32 ; xn = LN(h') bf16 ----
__global__ __launch_bounds__(256) void k_film_apply_ln(
    const float* __restrict__ h, const float* __restrict__ film,
    const float* __restrict__ g, const float* __restrict__ be,
    float* __restrict__ hs, u16* __restrict__ xn) {
  int row = blockIdx.x, t = threadIdx.x, b = row >> 4;
  int c = t * 4;
  f4 hv = *(const f4*)(h + (size_t)row * Dn + c);
  f4 sv = *(const f4*)(film + (size_t)b * 2048 + c);
  f4 shv = *(const f4*)(film + (size_t)b * 2048 + 1024 + c);
  f4 v;
  v.x = hv.x * (1.f + sv.x) + shv.x;
  v.y = hv.y * (1.f + sv.y) + shv.y;
  v.z = hv.z * (1.f + sv.z) + shv.z;
  v.w = hv.w * (1.f + sv.w) + shv.w;
  *(f4*)(hs + (size_t)row * Dn + c) = v;
  float s = v.x + v.y + v.z + v.w;
  float s2 = v.x * v.x + v.y * v.y + v.z * v.z + v.w * v.w;
  block_reduce2(s, s2);
  float m = s * (1.f / Dn);
  float var = fmaxf(s2 * (1.f / Dn) - m * m, 0.f);
  float rs = rsqrtf(var + EPSf);
  us4 o;
  o.x = f2bf((v.x - m) * rs * g[c + 0] + be[c + 0]);
  o.y = f2bf((v.y - m) * rs * g[c + 1] + be[c + 1]);
  o.z = f2bf((v.z - m) * rs * g[c + 2] + be[c + 2]);
  o.w = f2bf((v.w - m) * rs * g[c + 3] + be[c + 3]);
  *(us4*)(xn + (size_t)row * Dn + c) = o;
}

// ---- row LN f32 -> bf16 ----
__global__ __launch_bounds__(256) void k_ln(const float* __restrict__ x,
                                            u16* __restrict__ y,
                                            const float* __restrict__ g,
                                            const float* __restrict__ be) {
  int row = blockIdx.x, t = threadIdx.x;
  int c = t * 4;
  f4 v = *(const f4*)(x + (size_t)row * Dn + c);
  float s = v.x + v.y + v.z + v.w;
  float s2 = v.x * v.x + v.y * v.y + v.z * v.z + v.w * v.w;
  block_reduce2(s, s2);
  float m = s * (1.f / Dn);
  float var = fmaxf(s2 * (1.f / Dn) - m * m, 0.f);
  float rs = rsqrtf(var + EPSf);
  us4 o;
  o.x = f2bf((v.x - m) * rs * g[c + 0] + be[c + 0]);
  o.y = f2bf((v.y - m) * rs * g[c + 1] + be[c + 1]);
  o.z = f2bf((v.z - m) * rs * g[c + 2] + be[c + 2]);
  o.w = f2bf((v.w - m) * rs * g[c + 3] + be[c + 3]);
  *(us4*)(y + (size_t)row * Dn + c) = o;
}

#define LSTR 72

// ============ big MFMA GEMM: C[M][N] = A(bf16)[M][K] @ Bt[N][K]^T, 128x128 ============
// bmode: 0 = Bt bf16; 1 = B from f32 KV rows with fused LN.
// epi: 0 f32 out; 3 f32 token-scores (scale+bias+mask); 4 f32 *SCALE; 5 bf16 out.
__global__ __launch_bounds__(256) void k_gemm_mfma(
    const u16* __restrict__ A, int lda, long sA,
    const void* __restrict__ Bsrc, int ldb, long sB,
    float* __restrict__ C, int ldc, long sC,
    u16* __restrict__ Cb,
    const float* __restrict__ nmean, const float* __restrict__ nrstd, int sStat,
    const float* __restrict__ ngamma, const float* __restrict__ nbeta,
    int K, int bmode, int epi,
    const void* tokmask, const void* palign, const int* __restrict__ slots,
    const float* __restrict__ pbias, const float* __restrict__ sbias,
    const int* __restrict__ flagp, int Nkv) {
  int bz = blockIdx.z;
  A += (size_t)bz * sA;
  const u16* Bt = (const u16*)Bsrc + (bmode == 0 ? (size_t)bz * sB : 0);
  const float* KV = (const float*)Bsrc + (bmode == 1 ? (size_t)bz * sB : 0);
  if (C) C += (size_t)bz * sC;
  if (Cb) Cb += (size_t)bz * sC;
  const float* mn = nmean ? nmean + (size_t)bz * sStat : nullptr;
  const float* rsd = nrstd ? nrstd + (size_t)bz * sStat : nullptr;

  __shared__ u16 As[128 * LSTR];
  __shared__ u16 Bs[128 * LSTR];
  int t = threadIdx.x;
  int m0 = blockIdx.y * 128, n0 = blockIdx.x * 128;
  int w = t >> 6, l = t & 63;
  int wr = (w >> 1) * 64, wc = (w & 1) * 64;
  int lr = l & 15, lg = l >> 4;

  f32x4 acc[4][4];
#pragma unroll
  for (int m = 0; m < 4; m++)
#pragma unroll
    for (int n = 0; n < 4; n++) acc[m][n] = (f32x4){0.f, 0.f, 0.f, 0.f};

  for (int k0 = 0; k0 < K; k0 += 64) {
#pragma unroll
    for (int i = 0; i < 4; i++) {
      int idx = i * 256 + t;
      int r = idx >> 3, c = (idx & 7) * 8;
      *(short8*)&As[r * LSTR + c] =
          *(const short8*)(const void*)(A + (size_t)(m0 + r) * lda + k0 + c);
    }
    if (bmode == 0) {
#pragma unroll
      for (int i = 0; i < 4; i++) {
        int idx = i * 256 + t;
        int r = idx >> 3, c = (idx & 7) * 8;
        *(short8*)&Bs[r * LSTR + c] =
            *(const short8*)(const void*)(Bt + (size_t)(n0 + r) * ldb + k0 + c);
      }
    } else {
#pragma unroll
      for (int i = 0; i < 8; i++) {
        int idx = i * 256 + t;
        int r = idx >> 4, c = (idx & 15) * 4;
        f4 v = *(const f4*)(KV + (size_t)(n0 + r) * ldb + k0 + c);
        float m = mn[n0 + r], rs = rsd[n0 + r];
        us4 o;
        o.x = f2bf((v.x - m) * rs * ngamma[k0 + c + 0] + nbeta[k0 + c + 0]);
        o.y = f2bf((v.y - m) * rs * ngamma[k0 + c + 1] + nbeta[k0 + c + 1]);
        o.z = f2bf((v.z - m) * rs * ngamma[k0 + c + 2] + nbeta[k0 + c + 2]);
        o.w = f2bf((v.w - m) * rs * ngamma[k0 + c + 3] + nbeta[k0 + c + 3]);
        *(us4*)&Bs[r * LSTR + c] = o;
      }
    }
    __syncthreads();
#pragma unroll
    for (int ks = 0; ks < 2; ks++) {
      short8 a[4], b[4];
#pragma unroll
      for (int m = 0; m < 4; m++)
        a[m] = *(const short8*)&As[(wr + m * 16 + lr) * LSTR + ks * 32 + lg * 8];
#pragma unroll
      for (int n = 0; n < 4; n++)
        b[n] = *(const short8*)&Bs[(wc + n * 16 + lr) * LSTR + ks * 32 + lg * 8];
#pragma unroll
      for (int m = 0; m < 4; m++)
#pragma unroll
        for (int n = 0; n < 4; n++)
          acc[m][n] = __builtin_amdgcn_mfma_f32_16x16x32_bf16(a[m], b[n], acc[m][n], 0, 0, 0);
    }
    __syncthreads();
  }

  int m32 = (epi == 3) ? *flagp : 0;
#pragma unroll
  for (int m = 0; m < 4; m++) {
#pragma unroll
    for (int n = 0; n < 4; n++) {
#pragma unroll
      for (int i = 0; i < 4; i++) {
        int gr = m0 + wr + m * 16 + lg * 4 + i;
        int gc = n0 + wc + n * 16 + lr;
        float v = acc[m][n][i];
        if (epi == 3) {
          v *= SCALEf;
          int hh = gr >> 4, qq = gr & 15;
          size_t pidx = (size_t)(bz * Jn + qq) * Nkv + gc;
          bool pm = m32 ? (((const int*)palign)[pidx] != 0)
                        : (((const unsigned char*)palign)[pidx] != 0);
          if (pm) v += pbias[hh];
          int sl = slots[(size_t)bz * Nkv + gc];
          sl = sl < 0 ? 0 : (sl > 3 ? 3 : sl);
          v += sbias[hh * 4 + sl];
          bool tm = m32 ? (((const int*)tokmask)[(size_t)bz * Nkv + gc] != 0)
                        : (((const unsigned char*)tokmask)[(size_t)bz * Nkv + gc] != 0);
          if (!tm) v = -FLT_MAX;
        } else if (epi == 4) {
          v *= SCALEf;
        }
        if (epi == 5) {
          Cb[(size_t)gr * ldc + gc] = f2bf(v);
        } else {
          C[(size_t)gr * ldc + gc] = v;
        }
      }
    }
  }
}

// ============ skinny MFMA GEMM: 64x64 tile, 4 waves (1 strip each) ============
// epi: 0 f32+bias; 1 f32+bias+resid; 2 bf16+bias+gelu; 3 bf16+bias; 4 f32 raw.
// kzs: per-z K offset (split-K); normal callers pass 0.
__global__ __launch_bounds__(256) void k_gemm_sk(
    const u16* __restrict__ A, int lda, long sA,
    const u16* __restrict__ Bt, int ldb, long sB,
    float* __restrict__ C, int ldc, long sC,
    u16* __restrict__ Cb,
    const float* __restrict__ bias, const float* __restrict__ resid,
    int K, int epi, int kzs) {
  int bz = blockIdx.z;
  A += (size_t)bz * sA;
  Bt += (size_t)bz * sB;
  if (C) C += (size_t)bz * sC;
  if (Cb) Cb += (size_t)bz * sC;
  if (resid) resid += (size_t)bz * sC;
  int kofs = bz * kzs;
  __shared__ u16 As[64 * LSTR];
  __shared__ u16 Bs[64 * LSTR];
  int t = threadIdx.x;
  int m0 = blockIdx.y * 64, n0 = blockIdx.x * 64;
  int w = t >> 6, l = t & 63;
  int wr = w * 16;
  int lr = l & 15, lg = l >> 4;
  f32x4 acc[4];
#pragma unroll
  for (int n = 0; n < 4; n++) acc[n] = (f32x4){0.f, 0.f, 0.f, 0.f};
  for (int k0 = kofs; k0 < kofs + K; k0 += 64) {
#pragma unroll
    for (int i = 0; i < 2; i++) {
      int idx = i * 256 + t;
      int r = idx >> 3, c = (idx & 7) * 8;
      *(short8*)&As[r * LSTR + c] =
          *(const short8*)(const void*)(A + (size_t)(m0 + r) * lda + k0 + c);
      *(short8*)&Bs[r * LSTR + c] =
          *(const short8*)(const void*)(Bt + (size_t)(n0 + r) * ldb + k0 + c);
    }
    __syncthreads();
#pragma unroll
    for (int ks = 0; ks < 2; ks++) {
      short8 a = *(const short8*)&As[(wr + lr) * LSTR + ks * 32 + lg * 8];
#pragma unroll
      for (int n = 0; n < 4; n++) {
        short8 b = *(const short8*)&Bs[(n * 16 + lr) * LSTR + ks * 32 + lg * 8];
        acc[n] = __builtin_amdgcn_mfma_f32_16x16x32_bf16(a, b, acc[n], 0, 0, 0);
      }
    }
    __syncthreads();
  }
#pragma unroll
  for (int n = 0; n < 4; n++) {
#pragma unroll
    for (int i = 0; i < 4; i++) {
      int gr = m0 + wr + lg * 4 + i;
      int gc = n0 + n * 16 + lr;
      float v = acc[n][i];
      if (bias) v += bias[gc];
      if (epi == 1) v += resid[(size_t)gr * ldc + gc];
      if (epi == 2) {
        v = 0.5f * v * (1.f + erff(v * 0.70710678118654752f));
        Cb[(size_t)gr * ldc + gc] = f2bf(v);
      } else if (epi == 3) {
        Cb[(size_t)gr * ldc + gc] = f2bf(v);
      } else {
        C[(size_t)gr * ldc + gc] = v;
      }
    }
  }
}

// ---- split-K reduce: hs += p0+p1+p2+p3 + bias ----
__global__ __launch_bounds__(256) void k_red4(const float* __restrict__ part,
                                              const float* __restrict__ bias,
                                              float* __restrict__ hs) {
  int row = blockIdx.x, t = threadIdx.x;
  int c = t * 4;
  size_t o = (size_t)row * 1024 + c;
  f4 a = *(const f4*)(part + o);
  f4 b = *(const f4*)(part + o + 262144);
  f4 cc = *(const f4*)(part + o + 524288);
  f4 d = *(const f4*)(part + o + 786432);
  f4 r = *(const f4*)(hs + o);
  f4 bi = *(const f4*)(bias + c);
  r.x += a.x + b.x + cc.x + d.x + bi.x;
  r.y += a.y + b.y + cc.y + d.y + bi.y;
  r.z += a.z + b.z + cc.z + d.z + bi.z;
  r.w += a.w + b.w + cc.w + d.w + bi.w;
  *(f4*)(hs + o) = r;
}

// ============ per-head qw GEMM: qw[b,h*16+j,c] = sum_d qb[(b,j),h*64+d]*Wb[c,h*64+d] ====
// grid (N/64=16, M/64=4, H=16). K=64 (single iter).
__global__ __launch_bounds__(256) void k_qw_mfma(
    const u16* __restrict__ qb, const u16* __restrict__ Wb,
    u16* __restrict__ qwout) {
  int h = blockIdx.z;
  int m0 = blockIdx.y * 64, n0 = blockIdx.x * 64;
  __shared__ u16 As[64 * LSTR];
  __shared__ u16 Bs[64 * LSTR];
  int t = threadIdx.x;
  int w = t >> 6, l = t & 63;
  int wr = w * 16, lr = l & 15, lg = l >> 4;
#pragma unroll
  for (int i = 0; i < 2; i++) {
    int idx = i * 256 + t;
    int r = idx >> 3, c = (idx & 7) * 8;
    *(short8*)&As[r * LSTR + c] =
        *(const short8*)(const void*)(qb + (size_t)(m0 + r) * 1024 + h * 64 + c);
    *(short8*)&Bs[r * LSTR + c] =
        *(const short8*)(const void*)(Wb + (size_t)(n0 + r) * 1024 + h * 64 + c);
  }
  __syncthreads();
  f32x4 acc[4];
#pragma unroll
  for (int n = 0; n < 4; n++) acc[n] = (f32x4){0.f, 0.f, 0.f, 0.f};
#pragma unroll
  for (int ks = 0; ks < 2; ks++) {
    short8 a = *(const short8*)&As[(wr + lr) * LSTR + ks * 32 + lg * 8];
#pragma unroll
    for (int n = 0; n < 4; n++) {
      short8 b = *(const short8*)&Bs[(n * 16 + lr) * LSTR + ks * 32 + lg * 8];
      acc[n] = __builtin_amdgcn_mfma_f32_16x16x32_bf16(a, b, acc[n], 0, 0, 0);
    }
  }
#pragma unroll
  for (int n = 0; n < 4; n++) {
#pragma unroll
    for (int i = 0; i < 4; i++) {
      int row = m0 + wr + lg * 4 + i;  // = b*16 + j
      int col = n0 + n * 16 + lr;
      qwout[((size_t)(row >> 4) * 256 + h * 16 + (row & 15)) * 1024 + col] =
          f2bf(acc[n][i]);
    }
  }
}

// ============ per-head output GEMM: o[(b,j),h*64+d] = bias + sum_c ctx[b,h*16+j,c]*Wv[h*64+d,c]
// grid (M/64=4, H=16). N=64, K=1024.
__global__ __launch_bounds__(256) void k_ho_mfma(
    const u16* __restrict__ ctx, const u16* __restrict__ Wv,
    const float* __restrict__ bias, u16* __restrict__ o) {
  int h = blockIdx.y;
  int m0 = blockIdx.x * 64;
  __shared__ u16 As[64 * LSTR];
  __shared__ u16 Bs[64 * LSTR];
  int t = threadIdx.x;
  int w = t >> 6, l = t & 63;
  int wr = w * 16, lr = l & 15, lg = l >> 4;
  f32x4 acc[4];
#pragma unroll
  for (int n = 0; n < 4; n++) acc[n] = (f32x4){0.f, 0.f, 0.f, 0.f};
  for (int k0 = 0; k0 < 1024; k0 += 64) {
#pragma unroll
    for (int i = 0; i < 2; i++) {
      int idx = i * 256 + t;
      int r = idx >> 3, c = (idx & 7) * 8;
      int gr = m0 + r;  // b*16+j
      *(short8*)&As[r * LSTR + c] = *(const short8*)(const void*)(
          ctx + ((size_t)(gr >> 4) * 256 + h * 16 + (gr & 15)) * 1024 + k0 + c);
      *(short8*)&Bs[r * LSTR + c] = *(const short8*)(const void*)(
          Wv + (size_t)(h * 64 + r) * 1024 + k0 + c);
    }
    __syncthreads();
#pragma unroll
    for (int ks = 0; ks < 2; ks++) {
      short8 a = *(const short8*)&As[(wr + lr) * LSTR + ks * 32 + lg * 8];
#pragma unroll
      for (int n = 0; n < 4; n++) {
        short8 b = *(const short8*)&Bs[(n * 16 + lr) * LSTR + ks * 32 + lg * 8];
        acc[n] = __builtin_amdgcn_mfma_f32_16x16x32_bf16(a, b, acc[n], 0, 0, 0);
      }
    }
    __syncthreads();
  }
#pragma unroll
  for (int n = 0; n < 4; n++) {
#pragma unroll
    for (int i = 0; i < 4; i++) {
      int row = m0 + wr + lg * 4 + i;  // = b*16+j
      int col = n * 16 + lr;           // 0..63
      float v = acc[n][i] + bias[h * 64 + col];
      o[(size_t)row * 1024 + h * 64 + col] = f2bf(v);
    }
  }
}

// ---- row softmax f32 in -> bf16 out; ncols in {256, 2048} ----
__global__ __launch_bounds__(256) void k_softmax(const float* __restrict__ x,
                                                 u16* __restrict__ p, int ncols) {
  int row = blockIdx.x, t = threadIdx.x;
  const float* xr = x + (size_t)row * ncols;
  u16* pr = p + (size_t)row * ncols;
  int cnt = ncols >> 8;
  float r[8];
  float mx = -FLT_MAX;
  for (int i = 0; i < cnt; i++) {
    r[i] = xr[t + (i << 8)];
    mx = fmaxf(mx, r[i]);
  }
  mx = block_max_bcast(mx);
  float sm = 0.f;
  for (int i = 0; i < cnt; i++) {
    r[i] = expf(r[i] - mx);
    sm += r[i];
  }
  sm = block_sum_bcast(sm);
  float inv = 1.f / sm;
  for (int i = 0; i < cnt; i++) pr[t + (i << 8)] = f2bf(r[i] * inv);
}

// ---- self-attention over J=16 per (b,h); qkv f32 [256][3072]; out bf16 ----
__global__ __launch_bounds__(256) void k_sa(const float* __restrict__ qkv,
                                            u16* __restrict__ o) {
  int h = blockIdx.x, b = blockIdx.y, t = threadIdx.x;
  __shared__ float qs[16][68], ks[16][68], vs[16][68], ps[16][16];
  int rr = t >> 4, d4 = (t & 15) * 4;
  size_t base = (size_t)(b * Jn + rr) * 3072 + h * HDn + d4;
  *(f4*)&qs[rr][d4] = *(const f4*)(qkv + base);
  *(f4*)&ks[rr][d4] = *(const f4*)(qkv + base + 1024);
  *(f4*)&vs[rr][d4] = *(const f4*)(qkv + base + 2048);
  __syncthreads();
  int j1 = t >> 4, j2 = t & 15;
  float s = 0.f;
  for (int d = 0; d < 64; d++) s = fmaf(qs[j1][d], ks[j2][d], s);
  s *= SCALEf;
  float m = s;
#pragma unroll
  for (int oo = 8; oo; oo >>= 1) m = fmaxf(m, __shfl_xor(m, oo));
  float e = expf(s - m);
  float sm = e;
#pragma unroll
  for (int oo = 8; oo; oo >>= 1) sm += __shfl_xor(sm, oo);
  ps[j1][j2] = e / sm;
  __syncthreads();
  f4 acc = make_float4(0.f, 0.f, 0.f, 0.f);
#pragma unroll
  for (int k = 0; k < 16; k++) {
    float p = ps[j1][k];
    f4 v = *(const f4*)&vs[k][d4];
    acc.x += p * v.x; acc.y += p * v.y; acc.z += p * v.z; acc.w += p * v.w;
  }
  us4 ov;
  ov.x = f2bf(acc.x); ov.y = f2bf(acc.y); ov.z = f2bf(acc.z); ov.w = f2bf(acc.w);
  *(us4*)(o + (size_t)(b * Jn + j1) * Dn + h * HDn + d4) = ov;
}

extern "C" void kernel_launch(void* const* d_in, const int* in_sizes, int n_in,
                              void* d_out, int out_size, void* d_ws, size_t ws_size,
                              hipStream_t stream) {
  (void)in_sizes; (void)n_in; (void)out_size; (void)ws_size;
  const float* h       = (const float*)d_in[0];
  const float* cond    = (const float*)d_in[1];
  const float* tkv     = (const float*)d_in[2];
  const void*  tmask   = d_in[3];
  const void*  palign  = d_in[4];
  const int*   slots   = (const int*)d_in[5];
  const float* skv     = (const float*)d_in[6];
  const float* film_w  = (const float*)d_in[7];
  const float* film_b  = (const float*)d_in[8];
  const float* ln_g    = (const float*)d_in[9];
  const float* ln_b    = (const float*)d_in[10];
  const float* sa_in_w = (const float*)d_in[11];
  const float* sa_in_b = (const float*)d_in[12];
  const float* sa_out_w= (const float*)d_in[13];
  const float* sa_out_b= (const float*)d_in[14];
  const float* cq_w    = (const float*)d_in[15];
  const float* cq_b    = (const float*)d_in[16];
  const float* ck_w    = (const float*)d_in[17];
  const float* cv_w    = (const float*)d_in[19];
  const float* cv_b    = (const float*)d_in[20];
  const float* co_w    = (const float*)d_in[21];
  const float* co_b    = (const float*)d_in[22];
  const float* sp_in_w = (const float*)d_in[23];
  const float* sp_in_b = (const float*)d_in[24];
  const float* sp_out_w= (const float*)d_in[25];
  const float* sp_out_b= (const float*)d_in[26];
  const float* pbias   = (const float*)d_in[27];
  const float* sbias   = (const float*)d_in[28];
  const float* fw1     = (const float*)d_in[29];
  const float* fb1     = (const float*)d_in[30];
  const float* fw2     = (const float*)d_in[31];
  const float* fb2     = (const float*)d_in[32];

  char* wsp = (char*)d_ws;
  size_t off = 0;
  auto carve = [&](size_t bytes) -> char* {
    char* p = wsp + off;
    off = (off + bytes + 255) & ~(size_t)255;
    return p;
  };
  int*   flag  = (int*)carve(256);
  float* stTm  = (float*)carve((size_t)Bn * Ln * 4);
  float* stTr  = (float*)carve((size_t)Bn * Ln * 4);
  float* stSm  = (float*)carve((size_t)Bn * Sn * 4);
  float* stSr  = (float*)carve((size_t)Bn * Sn * 4);
  float* film  = (float*)carve((size_t)Bn * 2048 * 4);
  u16*   xn    = (u16*)carve((size_t)256 * Dn * 2);
  u16*   qb    = (u16*)carve((size_t)256 * Dn * 2);
  u16*   obuf  = (u16*)carve((size_t)256 * Dn * 2);
  u16*   qw    = (u16*)carve((size_t)Bn * 256 * Dn * 2);
  u16*   Pb    = (u16*)carve((size_t)Bn * 256 * Ln * 2);
  float* big   = (float*)carve((size_t)Bn * 256 * Ln * 4);  // scores/qkv/ctx/ubuf/part
  u16*   lnTt  = (u16*)carve((size_t)Bn * Dn * Ln * 2);
  u16*   lnSt  = (u16*)carve((size_t)Bn * Dn * Sn * 2);
  u16*   wsa   = (u16*)carve((size_t)3072 * Dn * 2);
  u16*   wso   = (u16*)carve((size_t)Dn * Dn * 2);
  u16*   wcq   = (u16*)carve((size_t)Dn * Dn * 2);
  u16*   wco   = (u16*)carve((size_t)Dn * Dn * 2);
  u16*   wspq  = (u16*)carve((size_t)Dn * Dn * 2);
  u16*   wspo  = (u16*)carve((size_t)Dn * Dn * 2);
  u16*   wf1   = (u16*)carve((size_t)4096 * Dn * 2);
  u16*   wf2   = (u16*)carve((size_t)Dn * 4096 * 2);
  u16*   wck   = (u16*)carve((size_t)Dn * Dn * 2);
  u16*   wspk  = (u16*)carve((size_t)Dn * Dn * 2);
  u16*   wcv   = (u16*)carve((size_t)Dn * Dn * 2);
  u16*   wsv   = (u16*)carve((size_t)Dn * Dn * 2);

  float* qkv    = big;                                  // f32 [256][3072], SA only
  float* scores = big;                                  // f32 [B][256][L]
  u16*   ctxb   = (u16*)big;                            // bf16 [B][256][1024]
  u16*   ubuf   = (u16*)big;                            // bf16 [256][4096], FFN
  float* part   = (float*)((char*)big + (4 << 20));     // f32 [4][256][1024], FFN2
  float* hs = (float*)d_out;

  const float* g0 = ln_g + 0 * Dn; const float* b0 = ln_b + 0 * Dn;
  const float* g1 = ln_g + 1 * Dn; const float* b1 = ln_b + 1 * Dn;
  const float* g2 = ln_g + 2 * Dn; const float* b2 = ln_b + 2 * Dn;
  const float* g3 = ln_g + 3 * Dn; const float* b3 = ln_b + 3 * Dn;
  const float* g4 = ln_g + 4 * Dn; const float* b4 = ln_b + 4 * Dn;
  const float* g5 = ln_g + 5 * Dn; const float* b5 = ln_b + 5 * Dn;

  dim3 blk(256);
  const float* nulf = nullptr;
  u16* nulb = nullptr;
  float* nulc = nullptr;

  // ---- prep ----
  k_probe<<<1, blk, 0, stream>>>((const int*)tmask, flag);
  k_rowstats<<<Bn * Ln, blk, 0, stream>>>(tkv, stTm, stTr);
  k_rowstats<<<Bn * Sn, blk, 0, stream>>>(skv, stSm, stSr);
  k_lnt<<<dim3(32, 64, Bn), blk, 0, stream>>>(tkv, stTm, stTr, g2, b2, lnTt, Ln);
  k_lnt<<<dim3(32, 8, Bn), blk, 0, stream>>>(skv, stSm, stSr, g4, b4, lnSt, Sn);
  k_wt<<<dim3(96, 32), blk, 0, stream>>>(sa_in_w, 3072, 0, Dn, wsa);
  k_wt<<<dim3(32, 32), blk, 0, stream>>>(sa_out_w, 1024, 0, Dn, wso);
  k_wt<<<dim3(32, 32), blk, 0, stream>>>(cq_w, 1024, 0, Dn, wcq);
  k_wt<<<dim3(32, 32), blk, 0, stream>>>(co_w, 1024, 0, Dn, wco);
  k_wt<<<dim3(32, 32), blk, 0, stream>>>(sp_in_w, 3072, 0, Dn, wspq);
  k_wt<<<dim3(32, 32), blk, 0, stream>>>(sp_out_w, 1024, 0, Dn, wspo);
  k_wt<<<dim3(128, 32), blk, 0, stream>>>(fw1, 4096, 0, Dn, wf1);
  k_wt<<<dim3(32, 128), blk, 0, stream>>>(fw2, 1024, 0, 4096, wf2);
  k_wt<<<dim3(32, 32), blk, 0, stream>>>(cv_w, 1024, 0, Dn, wcv);
  k_wt<<<dim3(32, 32), blk, 0, stream>>>(sp_in_w, 3072, 2048, Dn, wsv);
  k_cvt<<<512, blk, 0, stream>>>(ck_w, 1024, 0, wck);
  k_cvt<<<512, blk, 0, stream>>>(sp_in_w, 3072, 1024, wspk);
  k_film<<<dim3(8, Bn), blk, 0, stream>>>(cond, film_w, film_b, film);
  k_film_apply_ln<<<256, blk, 0, stream>>>(h, film, g0, b0, hs, xn);

  // ---- self-attention ----
  k_gemm_sk<<<dim3(48, 4, 1), blk, 0, stream>>>(
      xn, Dn, 0, wsa, Dn, 0, qkv, 3072, 0, nulb, sa_in_b, nulf, Dn, 0, 0);
  k_sa<<<dim3(Hn, Bn), blk, 0, stream>>>(qkv, obuf);
  k_gemm_sk<<<dim3(16, 4, 1), blk, 0, stream>>>(
      obuf, Dn, 0, wso, Dn, 0, hs, Dn, 0, nulb, sa_out_b, hs, Dn, 1, 0);

  // ---- masked token cross-attention (transpose trick) ----
  k_ln<<<256, blk, 0, stream>>>(hs, xn, g1, b1);
  k_gemm_sk<<<dim3(16, 4, 1), blk, 0, stream>>>(
      xn, Dn, 0, wcq, Dn, 0, nulc, Dn, 0, qb, cq_b, nulf, Dn, 3, 0);
  k_qw_mfma<<<dim3(16, 4, Hn), blk, 0, stream>>>(qb, wck, qw);
  k_gemm_mfma<<<dim3(16, 2, Bn), blk, 0, stream>>>(
      qw, Dn, (long)256 * Dn, tkv, Dn, (long)Ln * Dn,
      scores, Ln, (long)256 * Ln, nulb,
      stTm, stTr, Ln, g2, b2, Dn, 1, 3,
      tmask, palign, slots, pbias, sbias, flag, Ln);
  k_softmax<<<Bn * 256, blk, 0, stream>>>(scores, Pb, Ln);
  k_gemm_mfma<<<dim3(8, 2, Bn), blk, 0, stream>>>(
      Pb, Ln, (long)256 * Ln, lnTt, Ln, (long)Dn * Ln,
      nulc, Dn, (long)256 * Dn, ctxb,
      nulf, nulf, 0, nulf, nulf, Ln, 0, 5,
      nullptr, nullptr, nullptr, nulf, nulf, nullptr, 0);
  k_ho_mfma<<<dim3(4, Hn), blk, 0, stream>>>(ctxb, wcv, cv_b, obuf);
  k_gemm_sk<<<dim3(16, 4, 1), blk, 0, stream>>>(
      obuf, Dn, 0, wco, Dn, 0, hs, Dn, 0, nulb, co_b, hs, Dn, 1, 0);

  // ---- spatial cross-attention ----
  k_ln<<<256, blk, 0, stream>>>(hs, xn, g3, b3);
  k_gemm_sk<<<dim3(16, 4, 1), blk, 0, stream>>>(
      xn, Dn, 0, wspq, Dn, 0, nulc, Dn, 0, qb, sp_in_b, nulf, Dn, 3, 0);
  k_qw_mfma<<<dim3(16, 4, Hn), blk, 0, stream>>>(qb, wspk, qw);
  k_gemm_mfma<<<dim3(2, 2, Bn), blk, 0, stream>>>(
      qw, Dn, (long)256 * Dn, skv, Dn, (long)Sn * Dn,
      scores, Sn, (long)256 * Sn, nulb,
      stSm, stSr, Sn, g4, b4, Dn, 1, 4,
      nullptr, nullptr, nullptr, nulf, nulf, nullptr, Sn);
  k_softmax<<<Bn * 256, blk, 0, stream>>>(scores, Pb, Sn);
  k_gemm_mfma<<<dim3(8, 2, Bn), blk, 0, stream>>>(
      Pb, Sn, (long)256 * Sn, lnSt, Sn, (long)Dn * Sn,
      nulc, Dn, (long)256 * Dn, ctxb,
      nulf, nulf, 0, nulf, nulf, Sn, 0, 5,
      nullptr, nullptr, nullptr, nulf, nulf, nullptr, 0);
  k_ho_mfma<<<dim3(4, Hn), blk, 0, stream>>>(ctxb, wsv, sp_in_b + 2048, obuf);
  k_gemm_sk<<<dim3(16, 4, 1), blk, 0, stream>>>(
      obuf, Dn, 0, wspo, Dn, 0, hs, Dn, 0, nulb, sp_out_b, hs, Dn, 1, 0);

  // ---- FFN ----
  k_ln<<<256, blk, 0, stream>>>(hs, xn, g5, b5);
  k_gemm_sk<<<dim3(64, 4, 1), blk, 0, stream>>>(
      xn, Dn, 0, wf1, Dn, 0, nulc, 4096, 0, ubuf, fb1, nulf, Dn, 2, 0);
  k_gemm_sk<<<dim3(16, 4, 4), blk, 0, stream>>>(
      ubuf, 4096, 0, wf2, 4096, 0, part, Dn, (long)256 * Dn, nulb,
      nulf, nulf, 1024, 4, 1024);
  k_red4<<<256, blk, 0, stream>>>(part, fb2, hs);
}

// Round 6
// 764.245 us; speedup vs baseline: 2.8221x; 1.2847x over previous
//
#include <hip/hip_runtime.h>
#include <float.h>
#include <math.h>

// PoseHeadBlock, Round 6: all GEMMs pure-bf16 MFMA. k_lnt materializes LN'd kv
// in BOTH layouts (straight lnT for scores, transposed lnTt for ctx) so the
// fused-LN f32 staging path (7.75us/iter, 124us dispatch) is gone. Big GEMM
// retiled to 64x128 (more blocks/CU); BK=128 everywhere (half the serial
// K-iters). Transpose trick for both cross-attentions as before.

#define Bn 16
#define Jn 16
#define Ln 2048
#define Sn 256
#define Dn 1024
#define Hn 16
#define HDn 64

static const float EPSf = 1e-5f;
static const float SCALEf = 0.125f; // 1/sqrt(64)

typedef float4 f4;
typedef unsigned short u16;
typedef __attribute__((ext_vector_type(8))) short short8;
typedef __attribute__((ext_vector_type(4))) unsigned short us4;
typedef __attribute__((ext_vector_type(4))) float f32x4;

#define LSA 72    // LDS row stride (u16) for 64-wide K tiles
#define LSB 136   // LDS row stride (u16) for 128-wide K tiles

__device__ __forceinline__ u16 f2bf(float f) {
  unsigned u = __float_as_uint(f);
  unsigned r = (u + 0x7FFFu + ((u >> 16) & 1u)) >> 16;
  return (u16)r;
}

__device__ __forceinline__ float wave_sum(float v) {
#pragma unroll
  for (int o = 32; o; o >>= 1) v += __shfl_xor(v, o);
  return v;
}
__device__ __forceinline__ float wave_max(float v) {
#pragma unroll
  for (int o = 32; o; o >>= 1) v = fmaxf(v, __shfl_xor(v, o));
  return v;
}
__device__ __forceinline__ void block_reduce2(float& a, float& b) {
  __shared__ float la[4], lb[4];
  a = wave_sum(a); b = wave_sum(b);
  int t = threadIdx.x, w = t >> 6;
  __syncthreads();
  if ((t & 63) == 0) { la[w] = a; lb[w] = b; }
  __syncthreads();
  a = la[0] + la[1] + la[2] + la[3];
  b = lb[0] + lb[1] + lb[2] + lb[3];
}
__device__ __forceinline__ float block_max_bcast(float v) {
  __shared__ float lm[4];
  v = wave_max(v);
  int t = threadIdx.x;
  __syncthreads();
  if ((t & 63) == 0) lm[t >> 6] = v;
  __syncthreads();
  return fmaxf(fmaxf(lm[0], lm[1]), fmaxf(lm[2], lm[3]));
}
__device__ __forceinline__ float block_sum_bcast(float v) {
  __shared__ float ls[4];
  v = wave_sum(v);
  int t = threadIdx.x;
  __syncthreads();
  if ((t & 63) == 0) ls[t >> 6] = v;
  __syncthreads();
  return ls[0] + ls[1] + ls[2] + ls[3];
}

// ---- mask dtype probe: flag=1 -> int32 bools, 0 -> uint8 bools ----
__global__ __launch_bounds__(256) void k_probe(const int* __restrict__ tm, int* flag) {
  __shared__ int bad;
  int t = threadIdx.x;
  if (t == 0) bad = 0;
  __syncthreads();
  int loc = 0;
  for (int i = t; i < 4096; i += 256) {
    unsigned v = (unsigned)tm[i];
    if (v > 1u) loc = 1;
  }
  if (loc) bad = 1;
  __syncthreads();
  if (t == 0) *flag = bad ? 0 : 1;
}

// ---- per-row mean/rstd over D=1024 ----
__global__ __launch_bounds__(256) void k_rowstats(const float* __restrict__ x,
                                                  float* __restrict__ mean,
                                                  float* __restrict__ rstd) {
  int row = blockIdx.x, t = threadIdx.x;
  f4 v = *(const f4*)(x + (size_t)row * Dn + t * 4);
  float s = v.x + v.y + v.z + v.w;
  float s2 = v.x * v.x + v.y * v.y + v.z * v.z + v.w * v.w;
  block_reduce2(s, s2);
  if (t == 0) {
    float m = s * (1.f / Dn);
    float var = s2 * (1.f / Dn) - m * m;
    if (var < 0.f) var = 0.f;
    mean[row] = m;
    rstd[row] = rsqrtf(var + EPSf);
  }
}

// ---- LN kv -> bf16, BOTH layouts: outS[b][l][d] and outT[b][d][l] ----
__global__ __launch_bounds__(256) void k_lnt(const float* __restrict__ kv,
                                             const float* __restrict__ mean,
                                             const float* __restrict__ rstd,
                                             const float* __restrict__ g,
                                             const float* __restrict__ be,
                                             u16* __restrict__ outS,
                                             u16* __restrict__ outT, int Lkv) {
  int b = blockIdx.z, d0 = blockIdx.x * 32, l0 = blockIdx.y * 32;
  __shared__ float tile[32][33];
  int t = threadIdx.x;
  int r = t >> 3, c4 = (t & 7) * 4;
  const float* kvb = kv + (size_t)b * Lkv * Dn;
  f4 v = *(const f4*)(kvb + (size_t)(l0 + r) * Dn + d0 + c4);
  float m = mean[(size_t)b * Lkv + l0 + r], rs = rstd[(size_t)b * Lkv + l0 + r];
  float x0 = (v.x - m) * rs * g[d0 + c4 + 0] + be[d0 + c4 + 0];
  float x1 = (v.y - m) * rs * g[d0 + c4 + 1] + be[d0 + c4 + 1];
  float x2 = (v.z - m) * rs * g[d0 + c4 + 2] + be[d0 + c4 + 2];
  float x3 = (v.w - m) * rs * g[d0 + c4 + 3] + be[d0 + c4 + 3];
  tile[r][c4 + 0] = x0; tile[r][c4 + 1] = x1;
  tile[r][c4 + 2] = x2; tile[r][c4 + 3] = x3;
  us4 s;
  s.x = f2bf(x0); s.y = f2bf(x1); s.z = f2bf(x2); s.w = f2bf(x3);
  *(us4*)(outS + (size_t)b * Lkv * Dn + (size_t)(l0 + r) * Dn + d0 + c4) = s;
  __syncthreads();
  int dr = t >> 3, l4 = (t & 7) * 4;
  us4 o;
  o.x = f2bf(tile[l4 + 0][dr]);
  o.y = f2bf(tile[l4 + 1][dr]);
  o.z = f2bf(tile[l4 + 2][dr]);
  o.w = f2bf(tile[l4 + 3][dr]);
  *(us4*)(outT + (size_t)b * Dn * Lkv + (size_t)(d0 + dr) * Lkv + l0 + l4) = o;
}

// ---- weight f32 [K x ldw] (cols nofs..nofs+Nt) -> bf16 Bt[Nt][K] (transpose) ----
__global__ __launch_bounds__(256) void k_wt(const float* __restrict__ W, int ldw,
                                            int nofs, int K, u16* __restrict__ out) {
  int n0 = blockIdx.x * 32, k0 = blockIdx.y * 32;
  __shared__ float tile[32][33];
  int t = threadIdx.x;
  int r = t >> 3, c4 = (t & 7) * 4; // r = k-row, c = n-col
  f4 v = *(const f4*)(W + (size_t)(k0 + r) * ldw + nofs + n0 + c4);
  tile[r][c4 + 0] = v.x; tile[r][c4 + 1] = v.y;
  tile[r][c4 + 2] = v.z; tile[r][c4 + 3] = v.w;
  __syncthreads();
  int nr = t >> 3, k4 = (t & 7) * 4;
  us4 o;
  o.x = f2bf(tile[k4 + 0][nr]);
  o.y = f2bf(tile[k4 + 1][nr]);
  o.z = f2bf(tile[k4 + 2][nr]);
  o.w = f2bf(tile[k4 + 3][nr]);
  *(us4*)(out + (size_t)(n0 + nr) * K + k0 + k4) = o;
}

// ---- straight slice copy f32 -> bf16: out[r][0..1023] = W[r*ldw + nofs + c] ----
__global__ __launch_bounds__(256) void k_cvt(const float* __restrict__ W, int ldw,
                                             int nofs, u16* __restrict__ out) {
  size_t idx = ((size_t)blockIdx.x * 256 + threadIdx.x) * 8;
  int r = (int)(idx >> 10), c = (int)(idx & 1023);
  const float* src = W + (size_t)r * ldw + nofs + c;
  f4 v0 = *(const f4*)src;
  f4 v1 = *(const f4*)(src + 4);
  us4 o0, o1;
  o0.x = f2bf(v0.x); o0.y = f2bf(v0.y); o0.z = f2bf(v0.z); o0.w = f2bf(v0.w);
  o1.x = f2bf(v1.x); o1.y = f2bf(v1.y); o1.z = f2bf(v1.z); o1.w = f2bf(v1.w);
  *(us4*)(out + idx) = o0;
  *(us4*)(out + idx + 4) = o1;
}

// ---- film = cond @ film_w + film_b ; [B,2048] f32 ----
__global__ __launch_bounds__(256) void k_film(const float* __restrict__ cond,
                                              const float* __restrict__ fw,
                                              const float* __restrict__ fb,
                                              float* __restrict__ film) {
  int b = blockIdx.y, t = threadIdx.x;
  int n = blockIdx.x * 256 + t;
  __shared__ float cs[512];
  cs[t] = cond[b * 512 + t];
  cs[t + 256] = cond[b * 512 + 256 + t];
  __syncthreads();
  float acc = fb[n];
  for (int k = 0; k < 512; k++) acc = fmaf(cs[k], fw[(size_t)k * 2048 + n], acc);
  film[b * 2048 + n] = acc;
}

// ---- h' = h*(1+s)+sh -> hs f32 ; xn = LN(h') bf16 ----
__global__ __launch_bounds__(256) void k_film_apply_ln(
    const float* __restrict__ h, const float* __restrict__ film,
    const float* __restrict__ g, const float* __restrict__ be,
    float* __restrict__ hs, u16* __restrict__ xn) {
  int row = blockIdx.x, t = threadIdx.x, b = row >> 4;
  int c = t * 4;
  f4 hv = *(const f4*)(h + (size_t)row * Dn + c);
  f4 sv = *(const f4*)(film + (size_t)b * 2048 + c);
  f4 shv = *(const f4*)(film + (size_t)b * 2048 + 1024 + c);
  f4 v;
  v.x = hv.x * (1.f + sv.x) + shv.x;
  v.y = hv.y * (1.f + sv.y) + shv.y;
  v.z = hv.z * (1.f + sv.z) + shv.z;
  v.w = hv.w * (1.f + sv.w) + shv.w;
  *(f4*)(hs + (size_t)row * Dn + c) = v;
  float s = v.x + v.y + v.z + v.w;
  float s2 = v.x * v.x + v.y * v.y + v.z * v.z + v.w * v.w;
  block_reduce2(s, s2);
  float m = s * (1.f / Dn);
  float var = fmaxf(s2 * (1.f / Dn) - m * m, 0.f);
  float rs = rsqrtf(var + EPSf);
  us4 o;
  o.x = f2bf((v.x - m) * rs * g[c + 0] + be[c + 0]);
  o.y = f2bf((v.y - m) * rs * g[c + 1] + be[c + 1]);
  o.z = f2bf((v.z - m) * rs * g[c + 2] + be[c + 2]);
  o.w = f2bf((v.w - m) * rs * g[c + 3] + be[c + 3]);
  *(us4*)(xn + (size_t)row * Dn + c) = o;
}

// ---- row LN f32 -> bf16 ----
__global__ __launch_bounds__(256) void k_ln(const float* __restrict__ x,
                                            u16* __restrict__ y,
                                            const float* __restrict__ g,
                                            const float* __restrict__ be) {
  int row = blockIdx.x, t = threadIdx.x;
  int c = t * 4;
  f4 v = *(const f4*)(x + (size_t)row * Dn + c);
  float s = v.x + v.y + v.z + v.w;
  float s2 = v.x * v.x + v.y * v.y + v.z * v.z + v.w * v.w;
  block_reduce2(s, s2);
  float m = s * (1.f / Dn);
  float var = fmaxf(s2 * (1.f / Dn) - m * m, 0.f);
  float rs = rsqrtf(var + EPSf);
  us4 o;
  o.x = f2bf((v.x - m) * rs * g[c + 0] + be[c + 0]);
  o.y = f2bf((v.y - m) * rs * g[c + 1] + be[c + 1]);
  o.z = f2bf((v.z - m) * rs * g[c + 2] + be[c + 2]);
  o.w = f2bf((v.w - m) * rs * g[c + 3] + be[c + 3]);
  *(us4*)(y + (size_t)row * Dn + c) = o;
}

// ============ big MFMA GEMM: 64x128 tile, BK=128. C = A[M][K] @ Bt[N][K]^T ============
// epi: 0 f32 out; 3 f32 token-scores (scale+bias+mask); 4 f32 *SCALE; 5 bf16 out.
__global__ __launch_bounds__(256) void k_gs(
    const u16* __restrict__ A, int lda, long sA,
    const u16* __restrict__ Bt, int ldb, long sB,
    float* __restrict__ C, int ldc, long sC, u16* __restrict__ Cb,
    int K, int epi,
    const void* tokmask, const void* palign, const int* __restrict__ slots,
    const float* __restrict__ pbias, const float* __restrict__ sbias,
    const int* __restrict__ flagp, int Nkv) {
  int bz = blockIdx.z;
  A += (size_t)bz * sA;
  Bt += (size_t)bz * sB;
  if (C) C += (size_t)bz * sC;
  if (Cb) Cb += (size_t)bz * sC;

  __shared__ u16 As[64 * LSB];
  __shared__ u16 Bs[128 * LSB];
  int t = threadIdx.x;
  int m0 = blockIdx.y * 64, n0 = blockIdx.x * 128;
  int w = t >> 6, l = t & 63;
  int lr = l & 15, lg = l >> 4;

  f32x4 acc[4][2];
#pragma unroll
  for (int m = 0; m < 4; m++)
#pragma unroll
    for (int n = 0; n < 2; n++) acc[m][n] = (f32x4){0.f, 0.f, 0.f, 0.f};

  for (int k0 = 0; k0 < K; k0 += 128) {
#pragma unroll
    for (int i = 0; i < 4; i++) {
      int idx = i * 256 + t;
      int r = idx >> 4, c = (idx & 15) * 8;
      *(short8*)&As[r * LSB + c] =
          *(const short8*)(const void*)(A + (size_t)(m0 + r) * lda + k0 + c);
    }
#pragma unroll
    for (int i = 0; i < 8; i++) {
      int idx = i * 256 + t;
      int r = idx >> 4, c = (idx & 15) * 8;
      *(short8*)&Bs[r * LSB + c] =
          *(const short8*)(const void*)(Bt + (size_t)(n0 + r) * ldb + k0 + c);
    }
    __syncthreads();
#pragma unroll
    for (int ks = 0; ks < 4; ks++) {
      short8 a[4], b[2];
#pragma unroll
      for (int m = 0; m < 4; m++)
        a[m] = *(const short8*)&As[(m * 16 + lr) * LSB + ks * 32 + lg * 8];
#pragma unroll
      for (int n = 0; n < 2; n++)
        b[n] = *(const short8*)&Bs[(w * 32 + n * 16 + lr) * LSB + ks * 32 + lg * 8];
#pragma unroll
      for (int m = 0; m < 4; m++)
#pragma unroll
        for (int n = 0; n < 2; n++)
          acc[m][n] = __builtin_amdgcn_mfma_f32_16x16x32_bf16(a[m], b[n], acc[m][n], 0, 0, 0);
    }
    __syncthreads();
  }

  int m32 = (epi == 3) ? *flagp : 0;
#pragma unroll
  for (int m = 0; m < 4; m++) {
#pragma unroll
    for (int n = 0; n < 2; n++) {
#pragma unroll
      for (int i = 0; i < 4; i++) {
        int gr = m0 + m * 16 + lg * 4 + i;
        int gc = n0 + w * 32 + n * 16 + lr;
        float v = acc[m][n][i];
        if (epi == 3) {
          v *= SCALEf;
          int hh = gr >> 4, qq = gr & 15;
          size_t pidx = (size_t)(bz * Jn + qq) * Nkv + gc;
          bool pm = m32 ? (((const int*)palign)[pidx] != 0)
                        : (((const unsigned char*)palign)[pidx] != 0);
          if (pm) v += pbias[hh];
          int sl = slots[(size_t)bz * Nkv + gc];
          sl = sl < 0 ? 0 : (sl > 3 ? 3 : sl);
          v += sbias[hh * 4 + sl];
          bool tm = m32 ? (((const int*)tokmask)[(size_t)bz * Nkv + gc] != 0)
                        : (((const unsigned char*)tokmask)[(size_t)bz * Nkv + gc] != 0);
          if (!tm) v = -FLT_MAX;
        } else if (epi == 4) {
          v *= SCALEf;
        }
        if (epi == 5) {
          Cb[(size_t)gr * ldc + gc] = f2bf(v);
        } else {
          C[(size_t)gr * ldc + gc] = v;
        }
      }
    }
  }
}

// ============ skinny MFMA GEMM: 64x64 tile, BK=128, 4 waves ============
// epi: 0 f32+bias; 1 f32+bias+resid; 2 bf16+bias+gelu; 3 bf16+bias; 4 f32 raw.
// kzs: per-z K offset (split-K); normal callers pass 0.
__global__ __launch_bounds__(256) void k_gemm_sk(
    const u16* __restrict__ A, int lda, long sA,
    const u16* __restrict__ Bt, int ldb, long sB,
    float* __restrict__ C, int ldc, long sC,
    u16* __restrict__ Cb,
    const float* __restrict__ bias, const float* __restrict__ resid,
    int K, int epi, int kzs) {
  int bz = blockIdx.z;
  A += (size_t)bz * sA;
  Bt += (size_t)bz * sB;
  if (C) C += (size_t)bz * sC;
  if (Cb) Cb += (size_t)bz * sC;
  if (resid) resid += (size_t)bz * sC;
  int kofs = bz * kzs;
  __shared__ u16 As[64 * LSB];
  __shared__ u16 Bs[64 * LSB];
  int t = threadIdx.x;
  int m0 = blockIdx.y * 64, n0 = blockIdx.x * 64;
  int w = t >> 6, l = t & 63;
  int wr = w * 16;
  int lr = l & 15, lg = l >> 4;
  f32x4 acc[4];
#pragma unroll
  for (int n = 0; n < 4; n++) acc[n] = (f32x4){0.f, 0.f, 0.f, 0.f};
  for (int k0 = kofs; k0 < kofs + K; k0 += 128) {
#pragma unroll
    for (int i = 0; i < 4; i++) {
      int idx = i * 256 + t;
      int r = idx >> 4, c = (idx & 15) * 8;
      *(short8*)&As[r * LSB + c] =
          *(const short8*)(const void*)(A + (size_t)(m0 + r) * lda + k0 + c);
      *(short8*)&Bs[r * LSB + c] =
          *(const short8*)(const void*)(Bt + (size_t)(n0 + r) * ldb + k0 + c);
    }
    __syncthreads();
#pragma unroll
    for (int ks = 0; ks < 4; ks++) {
      short8 a = *(const short8*)&As[(wr + lr) * LSB + ks * 32 + lg * 8];
#pragma unroll
      for (int n = 0; n < 4; n++) {
        short8 b = *(const short8*)&Bs[(n * 16 + lr) * LSB + ks * 32 + lg * 8];
        acc[n] = __builtin_amdgcn_mfma_f32_16x16x32_bf16(a, b, acc[n], 0, 0, 0);
      }
    }
    __syncthreads();
  }
#pragma unroll
  for (int n = 0; n < 4; n++) {
#pragma unroll
    for (int i = 0; i < 4; i++) {
      int gr = m0 + wr + lg * 4 + i;
      int gc = n0 + n * 16 + lr;
      float v = acc[n][i];
      if (bias) v += bias[gc];
      if (epi == 1) v += resid[(size_t)gr * ldc + gc];
      if (epi == 2) {
        v = 0.5f * v * (1.f + erff(v * 0.70710678118654752f));
        Cb[(size_t)gr * ldc + gc] = f2bf(v);
      } else if (epi == 3) {
        Cb[(size_t)gr * ldc + gc] = f2bf(v);
      } else {
        C[(size_t)gr * ldc + gc] = v;
      }
    }
  }
}

// ---- split-K reduce: hs += p0+p1+p2+p3 + bias ----
__global__ __launch_bounds__(256) void k_red4(const float* __restrict__ part,
                                              const float* __restrict__ bias,
                                              float* __restrict__ hs) {
  int row = blockIdx.x, t = threadIdx.x;
  int c = t * 4;
  size_t o = (size_t)row * 1024 + c;
  f4 a = *(const f4*)(part + o);
  f4 b = *(const f4*)(part + o + 262144);
  f4 cc = *(const f4*)(part + o + 524288);
  f4 d = *(const f4*)(part + o + 786432);
  f4 r = *(const f4*)(hs + o);
  f4 bi = *(const f4*)(bias + c);
  r.x += a.x + b.x + cc.x + d.x + bi.x;
  r.y += a.y + b.y + cc.y + d.y + bi.y;
  r.z += a.z + b.z + cc.z + d.z + bi.z;
  r.w += a.w + b.w + cc.w + d.w + bi.w;
  *(f4*)(hs + o) = r;
}

// ============ per-head qw GEMM: qw[b,h*16+j,c] = sum_d qb[(b,j),h*64+d]*Wb[c,h*64+d] ====
// grid (16, 4, 16). K=64 single iter.
__global__ __launch_bounds__(256) void k_qw_mfma(
    const u16* __restrict__ qb, const u16* __restrict__ Wb,
    u16* __restrict__ qwout) {
  int h = blockIdx.z;
  int m0 = blockIdx.y * 64, n0 = blockIdx.x * 64;
  __shared__ u16 As[64 * LSA];
  __shared__ u16 Bs[64 * LSA];
  int t = threadIdx.x;
  int w = t >> 6, l = t & 63;
  int wr = w * 16, lr = l & 15, lg = l >> 4;
#pragma unroll
  for (int i = 0; i < 2; i++) {
    int idx = i * 256 + t;
    int r = idx >> 3, c = (idx & 7) * 8;
    *(short8*)&As[r * LSA + c] =
        *(const short8*)(const void*)(qb + (size_t)(m0 + r) * 1024 + h * 64 + c);
    *(short8*)&Bs[r * LSA + c] =
        *(const short8*)(const void*)(Wb + (size_t)(n0 + r) * 1024 + h * 64 + c);
  }
  __syncthreads();
  f32x4 acc[4];
#pragma unroll
  for (int n = 0; n < 4; n++) acc[n] = (f32x4){0.f, 0.f, 0.f, 0.f};
#pragma unroll
  for (int ks = 0; ks < 2; ks++) {
    short8 a = *(const short8*)&As[(wr + lr) * LSA + ks * 32 + lg * 8];
#pragma unroll
    for (int n = 0; n < 4; n++) {
      short8 b = *(const short8*)&Bs[(n * 16 + lr) * LSA + ks * 32 + lg * 8];
      acc[n] = __builtin_amdgcn_mfma_f32_16x16x32_bf16(a, b, acc[n], 0, 0, 0);
    }
  }
#pragma unroll
  for (int n = 0; n < 4; n++) {
#pragma unroll
    for (int i = 0; i < 4; i++) {
      int row = m0 + wr + lg * 4 + i;  // = b*16 + j
      int col = n0 + n * 16 + lr;
      qwout[((size_t)(row >> 4) * 256 + h * 16 + (row & 15)) * 1024 + col] =
          f2bf(acc[n][i]);
    }
  }
}

// ============ per-head output GEMM: o[(b,j),h*64+d] = bias + sum_c ctx[b,h*16+j,c]*Wv[h*64+d,c]
// grid (4, 16). N=64, K=1024, BK=128.
__global__ __launch_bounds__(256) void k_ho_mfma(
    const u16* __restrict__ ctx, const u16* __restrict__ Wv,
    const float* __restrict__ bias, u16* __restrict__ o) {
  int h = blockIdx.y;
  int m0 = blockIdx.x * 64;
  __shared__ u16 As[64 * LSB];
  __shared__ u16 Bs[64 * LSB];
  int t = threadIdx.x;
  int w = t >> 6, l = t & 63;
  int wr = w * 16, lr = l & 15, lg = l >> 4;
  f32x4 acc[4];
#pragma unroll
  for (int n = 0; n < 4; n++) acc[n] = (f32x4){0.f, 0.f, 0.f, 0.f};
  for (int k0 = 0; k0 < 1024; k0 += 128) {
#pragma unroll
    for (int i = 0; i < 4; i++) {
      int idx = i * 256 + t;
      int r = idx >> 4, c = (idx & 15) * 8;
      int gr = m0 + r;  // b*16+j
      *(short8*)&As[r * LSB + c] = *(const short8*)(const void*)(
          ctx + ((size_t)(gr >> 4) * 256 + h * 16 + (gr & 15)) * 1024 + k0 + c);
      *(short8*)&Bs[r * LSB + c] = *(const short8*)(const void*)(
          Wv + (size_t)(h * 64 + r) * 1024 + k0 + c);
    }
    __syncthreads();
#pragma unroll
    for (int ks = 0; ks < 4; ks++) {
      short8 a = *(const short8*)&As[(wr + lr) * LSB + ks * 32 + lg * 8];
#pragma unroll
      for (int n = 0; n < 4; n++) {
        short8 b = *(const short8*)&Bs[(n * 16 + lr) * LSB + ks * 32 + lg * 8];
        acc[n] = __builtin_amdgcn_mfma_f32_16x16x32_bf16(a, b, acc[n], 0, 0, 0);
      }
    }
    __syncthreads();
  }
#pragma unroll
  for (int n = 0; n < 4; n++) {
#pragma unroll
    for (int i = 0; i < 4; i++) {
      int row = m0 + wr + lg * 4 + i;  // = b*16+j
      int col = n * 16 + lr;           // 0..63
      float v = acc[n][i] + bias[h * 64 + col];
      o[(size_t)row * 1024 + h * 64 + col] = f2bf(v);
    }
  }
}

// ---- row softmax f32 in -> bf16 out; ncols in {256, 2048} ----
__global__ __launch_bounds__(256) void k_softmax(const float* __restrict__ x,
                                                 u16* __restrict__ p, int ncols) {
  int row = blockIdx.x, t = threadIdx.x;
  const float* xr = x + (size_t)row * ncols;
  u16* pr = p + (size_t)row * ncols;
  int cnt = ncols >> 8;
  float r[8];
  float mx = -FLT_MAX;
  for (int i = 0; i < cnt; i++) {
    r[i] = xr[t + (i << 8)];
    mx = fmaxf(mx, r[i]);
  }
  mx = block_max_bcast(mx);
  float sm = 0.f;
  for (int i = 0; i < cnt; i++) {
    r[i] = expf(r[i] - mx);
    sm += r[i];
  }
  sm = block_sum_bcast(sm);
  float inv = 1.f / sm;
  for (int i = 0; i < cnt; i++) pr[t + (i << 8)] = f2bf(r[i] * inv);
}

// ---- self-attention over J=16 per (b,h); qkv f32 [256][3072]; out bf16 ----
__global__ __launch_bounds__(256) void k_sa(const float* __restrict__ qkv,
                                            u16* __restrict__ o) {
  int h = blockIdx.x, b = blockIdx.y, t = threadIdx.x;
  __shared__ float qs[16][68], ks[16][68], vs[16][68], ps[16][16];
  int rr = t >> 4, d4 = (t & 15) * 4;
  size_t base = (size_t)(b * Jn + rr) * 3072 + h * HDn + d4;
  *(f4*)&qs[rr][d4] = *(const f4*)(qkv + base);
  *(f4*)&ks[rr][d4] = *(const f4*)(qkv + base + 1024);
  *(f4*)&vs[rr][d4] = *(const f4*)(qkv + base + 2048);
  __syncthreads();
  int j1 = t >> 4, j2 = t & 15;
  float s = 0.f;
  for (int d = 0; d < 64; d++) s = fmaf(qs[j1][d], ks[j2][d], s);
  s *= SCALEf;
  float m = s;
#pragma unroll
  for (int oo = 8; oo; oo >>= 1) m = fmaxf(m, __shfl_xor(m, oo));
  float e = expf(s - m);
  float sm = e;
#pragma unroll
  for (int oo = 8; oo; oo >>= 1) sm += __shfl_xor(sm, oo);
  ps[j1][j2] = e / sm;
  __syncthreads();
  f4 acc = make_float4(0.f, 0.f, 0.f, 0.f);
#pragma unroll
  for (int k = 0; k < 16; k++) {
    float p = ps[j1][k];
    f4 v = *(const f4*)&vs[k][d4];
    acc.x += p * v.x; acc.y += p * v.y; acc.z += p * v.z; acc.w += p * v.w;
  }
  us4 ov;
  ov.x = f2bf(acc.x); ov.y = f2bf(acc.y); ov.z = f2bf(acc.z); ov.w = f2bf(acc.w);
  *(us4*)(o + (size_t)(b * Jn + j1) * Dn + h * HDn + d4) = ov;
}

extern "C" void kernel_launch(void* const* d_in, const int* in_sizes, int n_in,
                              void* d_out, int out_size, void* d_ws, size_t ws_size,
                              hipStream_t stream) {
  (void)in_sizes; (void)n_in; (void)out_size; (void)ws_size;
  const float* h       = (const float*)d_in[0];
  const float* cond    = (const float*)d_in[1];
  const float* tkv     = (const float*)d_in[2];
  const void*  tmask   = d_in[3];
  const void*  palign  = d_in[4];
  const int*   slots   = (const int*)d_in[5];
  const float* skv     = (const float*)d_in[6];
  const float* film_w  = (const float*)d_in[7];
  const float* film_b  = (const float*)d_in[8];
  const float* ln_g    = (const float*)d_in[9];
  const float* ln_b    = (const float*)d_in[10];
  const float* sa_in_w = (const float*)d_in[11];
  const float* sa_in_b = (const float*)d_in[12];
  const float* sa_out_w= (const float*)d_in[13];
  const float* sa_out_b= (const float*)d_in[14];
  const float* cq_w    = (const float*)d_in[15];
  const float* cq_b    = (const float*)d_in[16];
  const float* ck_w    = (const float*)d_in[17];
  const float* cv_w    = (const float*)d_in[19];
  const float* cv_b    = (const float*)d_in[20];
  const float* co_w    = (const float*)d_in[21];
  const float* co_b    = (const float*)d_in[22];
  const float* sp_in_w = (const float*)d_in[23];
  const float* sp_in_b = (const float*)d_in[24];
  const float* sp_out_w= (const float*)d_in[25];
  const float* sp_out_b= (const float*)d_in[26];
  const float* pbias   = (const float*)d_in[27];
  const float* sbias   = (const float*)d_in[28];
  const float* fw1     = (const float*)d_in[29];
  const float* fb1     = (const float*)d_in[30];
  const float* fw2     = (const float*)d_in[31];
  const float* fb2     = (const float*)d_in[32];

  char* wsp = (char*)d_ws;
  size_t off = 0;
  auto carve = [&](size_t bytes) -> char* {
    char* p = wsp + off;
    off = (off + bytes + 255) & ~(size_t)255;
    return p;
  };
  int*   flag  = (int*)carve(256);
  float* stTm  = (float*)carve((size_t)Bn * Ln * 4);
  float* stTr  = (float*)carve((size_t)Bn * Ln * 4);
  float* stSm  = (float*)carve((size_t)Bn * Sn * 4);
  float* stSr  = (float*)carve((size_t)Bn * Sn * 4);
  float* film  = (float*)carve((size_t)Bn * 2048 * 4);
  u16*   xn    = (u16*)carve((size_t)256 * Dn * 2);
  u16*   qb    = (u16*)carve((size_t)256 * Dn * 2);
  u16*   obuf  = (u16*)carve((size_t)256 * Dn * 2);
  u16*   qw    = (u16*)carve((size_t)Bn * 256 * Dn * 2);
  u16*   Pb    = (u16*)carve((size_t)Bn * 256 * Ln * 2);
  float* big   = (float*)carve((size_t)Bn * 256 * Ln * 4);  // scores/qkv/ctxb/ubuf/part
  u16*   lnT   = (u16*)carve((size_t)Bn * Ln * Dn * 2);     // LN(tkv) straight
  u16*   lnTt  = (u16*)carve((size_t)Bn * Dn * Ln * 2);     // LN(tkv) transposed
  u16*   lnS   = (u16*)carve((size_t)Bn * Sn * Dn * 2);     // LN(skv) straight
  u16*   lnSt  = (u16*)carve((size_t)Bn * Dn * Sn * 2);     // LN(skv) transposed
  u16*   wsa   = (u16*)carve((size_t)3072 * Dn * 2);
  u16*   wso   = (u16*)carve((size_t)Dn * Dn * 2);
  u16*   wcq   = (u16*)carve((size_t)Dn * Dn * 2);
  u16*   wco   = (u16*)carve((size_t)Dn * Dn * 2);
  u16*   wspq  = (u16*)carve((size_t)Dn * Dn * 2);
  u16*   wspo  = (u16*)carve((size_t)Dn * Dn * 2);
  u16*   wf1   = (u16*)carve((size_t)4096 * Dn * 2);
  u16*   wf2   = (u16*)carve((size_t)Dn * 4096 * 2);
  u16*   wck   = (u16*)carve((size_t)Dn * Dn * 2);
  u16*   wspk  = (u16*)carve((size_t)Dn * Dn * 2);
  u16*   wcv   = (u16*)carve((size_t)Dn * Dn * 2);
  u16*   wsv   = (u16*)carve((size_t)Dn * Dn * 2);

  float* qkv    = big;                              // f32 [256][3072], SA only
  float* scores = big;                              // f32 [B][256][L]
  u16*   ctxb   = (u16*)big;                        // bf16 [B][256][1024]
  u16*   ubuf   = (u16*)big;                        // bf16 [256][4096], FFN
  float* part   = (float*)((char*)big + (4 << 20)); // f32 [4][256][1024], FFN2
  float* hs = (float*)d_out;

  const float* g0 = ln_g + 0 * Dn; const float* b0 = ln_b + 0 * Dn;
  const float* g1 = ln_g + 1 * Dn; const float* b1 = ln_b + 1 * Dn;
  const float* g2 = ln_g + 2 * Dn; const float* b2 = ln_b + 2 * Dn;
  const float* g3 = ln_g + 3 * Dn; const float* b3 = ln_b + 3 * Dn;
  const float* g4 = ln_g + 4 * Dn; const float* b4 = ln_b + 4 * Dn;
  const float* g5 = ln_g + 5 * Dn; const float* b5 = ln_b + 5 * Dn;

  dim3 blk(256);
  const float* nulf = nullptr;
  u16* nulb = nullptr;
  float* nulc = nullptr;

  // ---- prep ----
  k_probe<<<1, blk, 0, stream>>>((const int*)tmask, flag);
  k_rowstats<<<Bn * Ln, blk, 0, stream>>>(tkv, stTm, stTr);
  k_rowstats<<<Bn * Sn, blk, 0, stream>>>(skv, stSm, stSr);
  k_lnt<<<dim3(32, 64, Bn), blk, 0, stream>>>(tkv, stTm, stTr, g2, b2, lnT, lnTt, Ln);
  k_lnt<<<dim3(32, 8, Bn), blk, 0, stream>>>(skv, stSm, stSr, g4, b4, lnS, lnSt, Sn);
  k_wt<<<dim3(96, 32), blk, 0, stream>>>(sa_in_w, 3072, 0, Dn, wsa);
  k_wt<<<dim3(32, 32), blk, 0, stream>>>(sa_out_w, 1024, 0, Dn, wso);
  k_wt<<<dim3(32, 32), blk, 0, stream>>>(cq_w, 1024, 0, Dn, wcq);
  k_wt<<<dim3(32, 32), blk, 0, stream>>>(co_w, 1024, 0, Dn, wco);
  k_wt<<<dim3(32, 32), blk, 0, stream>>>(sp_in_w, 3072, 0, Dn, wspq);
  k_wt<<<dim3(32, 32), blk, 0, stream>>>(sp_out_w, 1024, 0, Dn, wspo);
  k_wt<<<dim3(128, 32), blk, 0, stream>>>(fw1, 4096, 0, Dn, wf1);
  k_wt<<<dim3(32, 128), blk, 0, stream>>>(fw2, 1024, 0, 4096, wf2);
  k_wt<<<dim3(32, 32), blk, 0, stream>>>(cv_w, 1024, 0, Dn, wcv);
  k_wt<<<dim3(32, 32), blk, 0, stream>>>(sp_in_w, 3072, 2048, Dn, wsv);
  k_cvt<<<512, blk, 0, stream>>>(ck_w, 1024, 0, wck);
  k_cvt<<<512, blk, 0, stream>>>(sp_in_w, 3072, 1024, wspk);
  k_film<<<dim3(8, Bn), blk, 0, stream>>>(cond, film_w, film_b, film);
  k_film_apply_ln<<<256, blk, 0, stream>>>(h, film, g0, b0, hs, xn);

  // ---- self-attention ----
  k_gemm_sk<<<dim3(48, 4, 1), blk, 0, stream>>>(
      xn, Dn, 0, wsa, Dn, 0, qkv, 3072, 0, nulb, sa_in_b, nulf, Dn, 0, 0);
  k_sa<<<dim3(Hn, Bn), blk, 0, stream>>>(qkv, obuf);
  k_gemm_sk<<<dim3(16, 4, 1), blk, 0, stream>>>(
      obuf, Dn, 0, wso, Dn, 0, hs, Dn, 0, nulb, sa_out_b, hs, Dn, 1, 0);

  // ---- masked token cross-attention (transpose trick) ----
  k_ln<<<256, blk, 0, stream>>>(hs, xn, g1, b1);
  k_gemm_sk<<<dim3(16, 4, 1), blk, 0, stream>>>(
      xn, Dn, 0, wcq, Dn, 0, nulc, Dn, 0, qb, cq_b, nulf, Dn, 3, 0);
  k_qw_mfma<<<dim3(16, 4, Hn), blk, 0, stream>>>(qb, wck, qw);
  k_gs<<<dim3(16, 4, Bn), blk, 0, stream>>>(
      qw, Dn, (long)256 * Dn, lnT, Dn, (long)Ln * Dn,
      scores, Ln, (long)256 * Ln, nulb, Dn, 3,
      tmask, palign, slots, pbias, sbias, flag, Ln);
  k_softmax<<<Bn * 256, blk, 0, stream>>>(scores, Pb, Ln);
  k_gs<<<dim3(8, 4, Bn), blk, 0, stream>>>(
      Pb, Ln, (long)256 * Ln, lnTt, Ln, (long)Dn * Ln,
      nulc, Dn, (long)256 * Dn, ctxb, Ln, 5,
      nullptr, nullptr, nullptr, nulf, nulf, nullptr, 0);
  k_ho_mfma<<<dim3(4, Hn), blk, 0, stream>>>(ctxb, wcv, cv_b, obuf);
  k_gemm_sk<<<dim3(16, 4, 1), blk, 0, stream>>>(
      obuf, Dn, 0, wco, Dn, 0, hs, Dn, 0, nulb, co_b, hs, Dn, 1, 0);

  // ---- spatial cross-attention ----
  k_ln<<<256, blk, 0, stream>>>(hs, xn, g3, b3);
  k_gemm_sk<<<dim3(16, 4, 1), blk, 0, stream>>>(
      xn, Dn, 0, wspq, Dn, 0, nulc, Dn, 0, qb, sp_in_b, nulf, Dn, 3, 0);
  k_qw_mfma<<<dim3(16, 4, Hn), blk, 0, stream>>>(qb, wspk, qw);
  k_gs<<<dim3(2, 4, Bn), blk, 0, stream>>>(
      qw, Dn, (long)256 * Dn, lnS, Dn, (long)Sn * Dn,
      scores, Sn, (long)256 * Sn, nulb, Dn, 4,
      nullptr, nullptr, nullptr, nulf, nulf, nullptr, Sn);
  k_softmax<<<Bn * 256, blk, 0, stream>>>(scores, Pb, Sn);
  k_gs<<<dim3(8, 4, Bn), blk, 0, stream>>>(
      Pb, Sn, (long)256 * Sn, lnSt, Sn, (long)Dn * Sn,
      nulc, Dn, (long)256 * Dn, ctxb, Sn, 5,
      nullptr, nullptr, nullptr, nulf, nulf, nullptr, 0);
  k_ho_mfma<<<dim3(4, Hn), blk, 0, stream>>>(ctxb, wsv, sp_in_b + 2048, obuf);
  k_gemm_sk<<<dim3(16, 4, 1), blk, 0, stream>>>(
      obuf, Dn, 0, wspo, Dn, 0, hs, Dn, 0, nulb, sp_out_b, hs, Dn, 1, 0);

  // ---- FFN ----
  k_ln<<<256, blk, 0, stream>>>(hs, xn, g5, b5);
  k_gemm_sk<<<dim3(64, 4, 1), blk, 0, stream>>>(
      xn, Dn, 0, wf1, Dn, 0, nulc, 4096, 0, ubuf, fb1, nulf, Dn, 2, 0);
  k_gemm_sk<<<dim3(16, 4, 4), blk, 0, stream>>>(
      ubuf, 4096, 0, wf2, 4096, 0, part, Dn, (long)256 * Dn, nulb,
      nulf, nulf, 1024, 4, 1024);
  k_red4<<<256, blk, 0, stream>>>(part, fb2, hs);
}